// Round 4
// baseline (339.720 us; speedup 1.0000x reference)
//
#include <hip/hip_runtime.h>
#include <hip/hip_bf16.h>
#include <math.h>

typedef __attribute__((ext_vector_type(8))) short bf16x8;
typedef __attribute__((ext_vector_type(4))) float f32x4;

__device__ __forceinline__ float eluf(float v){ return v > 0.f ? v : expm1f(v); }
__device__ __forceinline__ float sigf(float v){ return 1.f/(1.f+expf(-v)); }
__device__ __forceinline__ unsigned short f2bf(float f){
  unsigned u = __float_as_uint(f);
  u += 0x7FFFu + ((u >> 16) & 1u);          // round-to-nearest-even
  return (unsigned short)(u >> 16);
}
__device__ __forceinline__ float bf2f(short s){
  return __uint_as_float(((unsigned)(unsigned short)s) << 16);
}

// ---------------- block-wide sum & sumsq reduction ----------------
__device__ __forceinline__ void block_reduce2(float& a, float& b, float* sbuf){
  __syncthreads();
  for (int off = 32; off; off >>= 1){
    a += __shfl_down(a, off);
    b += __shfl_down(b, off);
  }
  int lane = threadIdx.x & 63, w = threadIdx.x >> 6;
  if (lane == 0){ sbuf[2*w] = a; sbuf[2*w+1] = b; }
  __syncthreads();
  if (threadIdx.x == 0){
    int nw = blockDim.x >> 6;
    float sa = 0.f, sb = 0.f;
    for (int i = 0; i < nw; i++){ sa += sbuf[2*i]; sb += sbuf[2*i+1]; }
    sbuf[0] = sa; sbuf[1] = sb;
  }
  __syncthreads();
  a = sbuf[0]; b = sbuf[1];
}

// ---------------- prep helpers ----------------
__device__ __forceinline__ float fold_sum(const float* __restrict__ w, int O, int I,
                                          int o, int i, int pa, int pb, int da, int db){
  float s = 0.f;
  for (int kh = 0; kh < 4; kh++){
    bool inh = (pb==0) ? (db==0 ? (kh==0) : (kh>=1)) : (db==0 ? (kh<=2) : (kh==3));
    if (!inh) continue;
    for (int kw = 0; kw < 4; kw++){
      bool inw = (pa==0) ? (da==0 ? (kw==0) : (kw>=1)) : (da==0 ? (kw<=2) : (kw==3));
      if (!inw) continue;
      s += w[((o*I + i)*4 + kh)*4 + kw];
    }
  }
  return s;
}
__device__ __forceinline__ void fold_elem(const float* __restrict__ w, float* __restrict__ CW,
                                          int O, int I, int l){
  int o = l % O; int q = l / O;
  int da = q & 1, db = (q>>1)&1, pa = (q>>2)&1, pb = (q>>3)&1, i = q>>4;
  CW[(((pb*2+pa)*4 + db*2+da)*I + i)*O + o] = fold_sum(w, O, I, o, i, pa, pb, da, db);
}
__device__ __forceinline__ void cvtc2_elem(const float* __restrict__ w, short* __restrict__ D, int l){
  int i = l & 15, t = (l>>4) & 15, o = l>>8;        // k = t*16 + i
  D[l] = (short)f2bf(w[(o*16 + i)*16 + t]);
}
__device__ __forceinline__ void cvtc3_elem(const float* __restrict__ w, short* __restrict__ D, int l){
  int i = l & 31, t = (l>>5) & 15, o = l>>9;        // k = t*32 + i
  D[l] = (short)f2bf(w[(o*32 + i)*16 + t]);
}
__device__ __forceinline__ void foldd1_elem(const float* __restrict__ w, short* __restrict__ D, int l){
  int i = l & 63, tap = (l>>6)&3, o = (l>>8)&31, ph = l>>13;
  D[l] = (short)f2bf(fold_sum(w, 32, 64, o, i, ph&1, ph>>1, tap&1, tap>>1));
}
__device__ __forceinline__ void foldd2_elem(const float* __restrict__ w, short* __restrict__ D, int l){
  int i = l & 31, tap = (l>>5)&3, o = (l>>7)&15, ph = l>>11;
  D[l] = (short)f2bf(fold_sum(w, 16, 32, o, i, ph&1, ph>>1, tap&1, tap>>1));
}

// ---------------- combined prep: weight transposes (blocks 0..1191) + small packs ----------------
__global__ __launch_bounds__(256) void prep_combined(
  const float* __restrict__ efc,  short* __restrict__ Defc,
  const float* __restrict__ dfc2, short* __restrict__ Ddfc2,
  const float* __restrict__ outw, short* __restrict__ Dout,
  const float* __restrict__ corew,short* __restrict__ Dcore,
  const float* __restrict__ dfc1, short* __restrict__ Ddfc1,
  const float* __restrict__ renc, short* __restrict__ Drenc,
  const float* __restrict__ ctx,  short* __restrict__ Dctx,
  const float* __restrict__ att1, short* __restrict__ Datt1,
  const float* __restrict__ d3w, float* __restrict__ CWT3,
  const float* __restrict__ c2w, short* __restrict__ BtC2,
  const float* __restrict__ c3w, short* __restrict__ BtC3,
  const float* __restrict__ d1w, short* __restrict__ BD1,
  const float* __restrict__ d2w, short* __restrict__ BD2,
  const float* __restrict__ state, short* __restrict__ SBF,
  short* __restrict__ TOTb)
{
  int bx = blockIdx.x;
  if (bx >= 1192){
    const int F3=256, P2=F3+8192, P3=P2+32768, P4=P3+32768, P5=P4+8192,
              ST=P5+98304, TOTAL=ST+4608;
    for (int l = (bx-1192)*256 + threadIdx.x; l < TOTAL; l += 256*256){
      if (l < F3)      fold_elem(d3w, CWT3, 1, 16, l);
      else if (l < P2) cvtc2_elem(c2w, BtC2, l - F3);
      else if (l < P3) cvtc3_elem(c3w, BtC3, l - P2);
      else if (l < P4) foldd1_elem(d1w, BD1, l - P3);
      else if (l < P5) foldd2_elem(d2w, BD2, l - P4);
      else if (l < ST){
        int q = l - P5;             // state -> bf16 [384][256], zero pad
        int n = q >> 8, k = q & 255;
        SBF[q] = (k < 250) ? (short)f2bf(state[n*250 + k]) : (short)0;
      } else {
        int q = l - ST;             // zero TOT pad cols: 250..255, 506..511
        int row = q / 12, cc = q % 12;
        int col = cc < 6 ? 250 + cc : 506 + (cc - 6);
        TOTb[row*1024 + col] = 0;
      }
    }
    return;
  }
  const float* W; short* D; int K, N, Kp, base, mode = 0;
  if      (bx < 512) { W=efc;  D=Defc;  K=4096; N=512;  Kp=4096; base=0;    }
  else if (bx < 1024){ W=dfc2; D=Ddfc2; K=512;  N=4096; Kp=512;  base=512;  }
  else if (bx < 1088){ W=outw; D=Dout;  K=1012; N=250;  Kp=1024; base=1024; mode=2; }
  else if (bx < 1120){ W=corew;D=Dcore; K=500;  N=250;  Kp=512;  base=1088; mode=1; }
  else if (bx < 1152){ W=dfc1; D=Ddfc1; K=250;  N=512;  Kp=256;  base=1120; }
  else if (bx < 1168){ W=renc; D=Drenc; K=250;  N=250;  Kp=256;  base=1152; }
  else if (bx < 1184){ W=ctx;  D=Dctx;  K=250;  N=250;  Kp=256;  base=1168; }
  else               { W=att1; D=Datt1; K=250;  N=100;  Kp=256;  base=1184; }
  int t = bx - base;
  int tpr = Kp >> 6;
  int tk = t % tpr, tn = t / tpr;
  __shared__ short tile[64][65];
  int c = threadIdx.x & 63, r4 = threadIdx.x >> 6;
  int n0 = tn*64, k0 = tk*64;
  #pragma unroll 4
  for (int p = 0; p < 16; p++){
    int r = r4*16 + p;
    int k = k0 + r, n = n0 + c;
    int ksrc = k; bool valid;
    if (mode == 0) valid = (k < K);
    else if (mode == 1){ valid = (k < 250) || (k >= 256 && k < 506); ksrc = k < 256 ? k : k - 6; }
    else { valid = (k < 250) || (k >= 256 && k < 506) || (k >= 512);
           ksrc = k < 256 ? k : (k < 512 ? k - 6 : k - 12); }
    float v = (valid && n < N) ? W[(size_t)ksrc*N + n] : 0.f;
    tile[c][r] = (short)f2bf(v);
  }
  __syncthreads();
  #pragma unroll 4
  for (int p = 0; p < 16; p++){
    int nn = r4*16 + p;
    int n = n0 + nn;
    if (n < N) D[(size_t)n*Kp + k0 + c] = tile[nn][c];
  }
}

// ---------------- MFMA bf16 split-K GEMM, bf16 A ----------------
__global__ __launch_bounds__(256) void gemm_mfma(
    const short* __restrict__ Ab, const short* __restrict__ Bt,
    float* __restrict__ P, int M, int N, int Kp, int Kc)
{
  __shared__ __align__(16) short As[64*32];
  __shared__ __align__(16) short Bs[64*32];
  int tid = threadIdx.x;
  int bm = blockIdx.y*64, bn = blockIdx.x*64;
  int kb = blockIdx.z * Kc;
  int kend = kb + Kc;

  int r = tid >> 2, c = tid & 3;
  const short* Arow = Ab + (size_t)(bm + r)*Kp;
  int gn = bn + r;
  bool bval = gn < N;
  const short* Brow = Bt + (size_t)gn*Kp;

  uint4 hA, hB;
  auto load_regs = [&](int k0){
    hA = *(const uint4*)&Arow[k0 + c*8];
    hB = bval ? *(const uint4*)&Brow[k0 + c*8] : make_uint4(0,0,0,0);
  };
  auto write_lds = [&](){
    *(uint4*)&As[r*32 + c*8] = hA;
    *(uint4*)&Bs[r*32 + c*8] = hB;
  };

  int wave = tid >> 6;
  int ln = tid & 15, quad = (tid >> 4) & 3;
  int wr = (wave >> 1) * 32, wc = (wave & 1) * 32;

  f32x4 zero = {0.f, 0.f, 0.f, 0.f};
  f32x4 acc[2][2] = {{zero, zero}, {zero, zero}};

  load_regs(kb);
  write_lds();
  __syncthreads();
  for (int k0 = kb; k0 < kend; k0 += 32){
    int nxt = k0 + 32;
    if (nxt < kend) load_regs(nxt);
    bf16x8 a0 = *(const bf16x8*)&As[(wr +      ln)*32 + quad*8];
    bf16x8 a1 = *(const bf16x8*)&As[(wr + 16 + ln)*32 + quad*8];
    bf16x8 b0 = *(const bf16x8*)&Bs[(wc +      ln)*32 + quad*8];
    bf16x8 b1 = *(const bf16x8*)&Bs[(wc + 16 + ln)*32 + quad*8];
    acc[0][0] = __builtin_amdgcn_mfma_f32_16x16x32_bf16(a0, b0, acc[0][0], 0, 0, 0);
    acc[0][1] = __builtin_amdgcn_mfma_f32_16x16x32_bf16(a0, b1, acc[0][1], 0, 0, 0);
    acc[1][0] = __builtin_amdgcn_mfma_f32_16x16x32_bf16(a1, b0, acc[1][0], 0, 0, 0);
    acc[1][1] = __builtin_amdgcn_mfma_f32_16x16x32_bf16(a1, b1, acc[1][1], 0, 0, 0);
    __syncthreads();
    if (nxt < kend){ write_lds(); __syncthreads(); }
  }

  float* Pout = P + (size_t)blockIdx.z*M*N;
  #pragma unroll
  for (int t = 0; t < 2; t++)
    #pragma unroll
    for (int u = 0; u < 2; u++)
      #pragma unroll
      for (int j = 0; j < 4; j++){
        int row = bm + wr + t*16 + quad*4 + j;
        int col = bn + wc + u*16 + ln;
        if (col < N) Pout[(size_t)row*N + col] = acc[t][u][j];
      }
}

// ---------------- conv2 as gather-GEMM: A im2col'd from E1b on the fly ----------------
// M = 384*256 rows (n,pos), N = 32 ch, K = 256 (tap16 x ch16). Tile 128x32, grid M/128 = 768.
// Out: raw conv2 (pre-bias, pre-LN) bf16 at [(n*256+pos)*32 + ch]  (= (n, a, b, ch) layout).
__global__ __launch_bounds__(256) void gemm_conv2g(
    const short* __restrict__ In, const short* __restrict__ Bt,
    short* __restrict__ Out)
{
  __shared__ __align__(16) short As[128*32];
  __shared__ __align__(16) short Bs[32*32];
  int tid = threadIdx.x;
  int bm = blockIdx.x*128;

  // A staging: 128 rows, 2x uint4 per thread
  int ra = tid >> 1, ca = (tid & 1)*16;
  int gr = bm + ra;
  int n = gr >> 8, pos = gr & 255;
  int oa = pos >> 4, ob = pos & 15;
  const short* ibase = In + (size_t)n*16384;
  // B staging: first 128 threads, 32 rows x 4 uint4
  int rb = tid >> 2, cb = (tid & 3)*8;
  const short* Brow = Bt + rb*256;
  bool bact = tid < 128;

  uint4 hA0, hA1, hB;
  auto load_regs = [&](int k0){
    #pragma unroll
    for (int h = 0; h < 2; h++){
      int k = k0 + ca + h*8;
      int tap = k >> 4;
      int ai = 2*oa + (tap & 3) - 1, bi = 2*ob + (tap >> 2) - 1;
      bool v = ((unsigned)ai < 32u) && ((unsigned)bi < 32u);
      uint4 tv = v ? *(const uint4*)&ibase[ai*512 + bi*16 + (k & 15)] : make_uint4(0,0,0,0);
      if (h == 0) hA0 = tv; else hA1 = tv;
    }
    if (bact) hB = *(const uint4*)&Brow[k0 + cb];
  };
  auto write_lds = [&](){
    *(uint4*)&As[ra*32 + ca] = hA0;
    *(uint4*)&As[ra*32 + ca + 8] = hA1;
    if (bact) *(uint4*)&Bs[rb*32 + cb] = hB;
  };

  int wave = tid >> 6, ln = tid & 15, quad = (tid >> 4) & 3;
  int wr = wave * 32;

  f32x4 zero = {0.f,0.f,0.f,0.f};
  f32x4 acc[2][2] = {{zero,zero},{zero,zero}};
  load_regs(0); write_lds(); __syncthreads();
  for (int k0 = 0; k0 < 256; k0 += 32){
    int nxt = k0 + 32;
    if (nxt < 256) load_regs(nxt);
    bf16x8 a0 = *(const bf16x8*)&As[(wr +      ln)*32 + quad*8];
    bf16x8 a1 = *(const bf16x8*)&As[(wr + 16 + ln)*32 + quad*8];
    bf16x8 b0 = *(const bf16x8*)&Bs[(     ln)*32 + quad*8];
    bf16x8 b1 = *(const bf16x8*)&Bs[(16 + ln)*32 + quad*8];
    acc[0][0] = __builtin_amdgcn_mfma_f32_16x16x32_bf16(a0, b0, acc[0][0], 0, 0, 0);
    acc[0][1] = __builtin_amdgcn_mfma_f32_16x16x32_bf16(a0, b1, acc[0][1], 0, 0, 0);
    acc[1][0] = __builtin_amdgcn_mfma_f32_16x16x32_bf16(a1, b0, acc[1][0], 0, 0, 0);
    acc[1][1] = __builtin_amdgcn_mfma_f32_16x16x32_bf16(a1, b1, acc[1][1], 0, 0, 0);
    __syncthreads();
    if (nxt < 256){ write_lds(); __syncthreads(); }
  }
  #pragma unroll
  for (int t = 0; t < 2; t++)
    #pragma unroll
    for (int u = 0; u < 2; u++)
      #pragma unroll
      for (int j = 0; j < 4; j++){
        int row = bm + wr + t*16 + quad*4 + j;
        int col = u*16 + ln;
        Out[(size_t)row*32 + col] = (short)f2bf(acc[t][u][j]);
      }
}

// ---------------- per-sample LN(8192)+ELU in place on bf16 (conv2 output) ----------------
__global__ __launch_bounds__(256) void ln_conv2_act(
    short* __restrict__ E, const float* __restrict__ bias)
{
  __shared__ float sbuf[16];
  int n = blockIdx.x, tid = threadIdx.x;
  short* p = E + (size_t)n*8192;
  float vv[32];
  float s = 0.f, s2 = 0.f;
  #pragma unroll
  for (int t = 0; t < 4; t++){
    bf16x8 v8 = *(const bf16x8*)&p[(t*256 + tid)*8];
    #pragma unroll
    for (int j = 0; j < 8; j++){
      int i = (t*256 + tid)*8 + j;
      float v = bf2f(v8[j]) + bias[i & 31];
      vv[t*8+j] = v; s += v; s2 += v*v;
    }
  }
  block_reduce2(s, s2, sbuf);
  float m = s*(1.f/8192.f);
  float rs = rsqrtf(s2*(1.f/8192.f) - m*m + 1e-5f);
  #pragma unroll
  for (int t = 0; t < 4; t++){
    bf16x8 o8;
    #pragma unroll
    for (int j = 0; j < 8; j++)
      o8[j] = (short)f2bf(eluf((vv[t*8+j]-m)*rs));
    *(bf16x8*)&p[(t*256 + tid)*8] = o8;
  }
}

// ---------------- conv3 as gather-GEMM: A im2col'd from activated E2b ----------------
// M = 384*64 rows (n,pos8x8), N = 64, K = 512 (tap16 x ch32). Tile 64x64, grid 384.
// Out: raw conv3 fp32 at [row*64 + col] (-> P rows n*4096 contiguous per sample).
__global__ __launch_bounds__(256) void gemm_conv3g(
    const short* __restrict__ In, const short* __restrict__ Bt,
    float* __restrict__ P)
{
  __shared__ __align__(16) short As[64*32];
  __shared__ __align__(16) short Bs[64*32];
  int tid = threadIdx.x;
  int bm = blockIdx.x*64;

  int r = tid >> 2, c = tid & 3;
  int gr = bm + r;
  int n = gr >> 6, pos = gr & 63;
  int oa = pos >> 3, ob = pos & 7;
  const short* ibase = In + (size_t)n*8192;
  const short* Brow = Bt + r*512;

  uint4 hA, hB;
  auto load_regs = [&](int k0){
    int k = k0 + c*8;
    int tap = k >> 5;
    int ai = 2*oa + (tap & 3) - 1, bi = 2*ob + (tap >> 2) - 1;
    bool v = ((unsigned)ai < 16u) && ((unsigned)bi < 16u);
    hA = v ? *(const uint4*)&ibase[(ai*16 + bi)*32 + (k & 31)] : make_uint4(0,0,0,0);
    hB = *(const uint4*)&Brow[k];
  };
  auto write_lds = [&](){
    *(uint4*)&As[r*32 + c*8] = hA;
    *(uint4*)&Bs[r*32 + c*8] = hB;
  };

  int wave = tid >> 6, ln = tid & 15, quad = (tid >> 4) & 3;
  int wr = (wave >> 1) * 32, wc = (wave & 1) * 32;

  f32x4 zero = {0.f,0.f,0.f,0.f};
  f32x4 acc[2][2] = {{zero,zero},{zero,zero}};
  load_regs(0); write_lds(); __syncthreads();
  for (int k0 = 0; k0 < 512; k0 += 32){
    int nxt = k0 + 32;
    if (nxt < 512) load_regs(nxt);
    bf16x8 a0 = *(const bf16x8*)&As[(wr +      ln)*32 + quad*8];
    bf16x8 a1 = *(const bf16x8*)&As[(wr + 16 + ln)*32 + quad*8];
    bf16x8 b0 = *(const bf16x8*)&Bs[(wc +      ln)*32 + quad*8];
    bf16x8 b1 = *(const bf16x8*)&Bs[(wc + 16 + ln)*32 + quad*8];
    acc[0][0] = __builtin_amdgcn_mfma_f32_16x16x32_bf16(a0, b0, acc[0][0], 0, 0, 0);
    acc[0][1] = __builtin_amdgcn_mfma_f32_16x16x32_bf16(a0, b1, acc[0][1], 0, 0, 0);
    acc[1][0] = __builtin_amdgcn_mfma_f32_16x16x32_bf16(a1, b0, acc[1][0], 0, 0, 0);
    acc[1][1] = __builtin_amdgcn_mfma_f32_16x16x32_bf16(a1, b1, acc[1][1], 0, 0, 0);
    __syncthreads();
    if (nxt < 512){ write_lds(); __syncthreads(); }
  }
  #pragma unroll
  for (int t = 0; t < 2; t++)
    #pragma unroll
    for (int u = 0; u < 2; u++)
      #pragma unroll
      for (int j = 0; j < 4; j++){
        int row = bm + wr + t*16 + quad*4 + j;
        int col = wc + u*16 + ln;
        P[(size_t)row*64 + col] = acc[t][u][j];
      }
}

// ---------------- core GEMM: A gathered from padded TOT (pair fusion) ----------------
__global__ __launch_bounds__(256) void gemm_core_mfma(
    const short* __restrict__ Tb, const short* __restrict__ Bt,
    float* __restrict__ P, int M, int N, int Kc)
{
  __shared__ __align__(16) short As[64*32];
  __shared__ __align__(16) short Bs[64*32];
  int tid = threadIdx.x;
  int bm = blockIdx.y*64, bn = blockIdx.x*64;
  int kb = blockIdx.z * Kc;
  int kend = kb + Kc;

  int r = tid >> 2, c = tid & 3;
  int gr = bm + r;
  int jj2 = gr % 7, fi2 = gr / 7;
  int ii = fi2 & 7, j2 = fi2 >> 3;
  int jidx = jj2 < ii ? jj2 : jj2 + 1;
  const short* own = Tb + (size_t)fi2*1024;
  const short* oth = Tb + (size_t)(j2*8 + jidx)*1024;
  int gn = bn + r;
  bool bval = gn < N;
  const short* Brow = Bt + (size_t)gn*512;

  uint4 hA, hB;
  auto load_regs = [&](int k0){
    int kk = k0 + c*8;
    const short* src = (kk & 256) ? oth : own;
    hA = *(const uint4*)&src[kk & 255];
    hB = bval ? *(const uint4*)&Brow[kk] : make_uint4(0,0,0,0);
  };
  auto write_lds = [&](){
    *(uint4*)&As[r*32 + c*8] = hA;
    *(uint4*)&Bs[r*32 + c*8] = hB;
  };

  int wave = tid >> 6;
  int ln = tid & 15, quad = (tid >> 4) & 3;
  int wr = (wave >> 1) * 32, wc = (wave & 1) * 32;

  f32x4 zero = {0.f, 0.f, 0.f, 0.f};
  f32x4 acc[2][2] = {{zero, zero}, {zero, zero}};

  load_regs(kb);
  write_lds();
  __syncthreads();
  for (int k0 = kb; k0 < kend; k0 += 32){
    int nxt = k0 + 32;
    if (nxt < kend) load_regs(nxt);
    bf16x8 a0 = *(const bf16x8*)&As[(wr +      ln)*32 + quad*8];
    bf16x8 a1 = *(const bf16x8*)&As[(wr + 16 + ln)*32 + quad*8];
    bf16x8 b0 = *(const bf16x8*)&Bs[(wc +      ln)*32 + quad*8];
    bf16x8 b1 = *(const bf16x8*)&Bs[(wc + 16 + ln)*32 + quad*8];
    acc[0][0] = __builtin_amdgcn_mfma_f32_16x16x32_bf16(a0, b0, acc[0][0], 0, 0, 0);
    acc[0][1] = __builtin_amdgcn_mfma_f32_16x16x32_bf16(a0, b1, acc[0][1], 0, 0, 0);
    acc[1][0] = __builtin_amdgcn_mfma_f32_16x16x32_bf16(a1, b0, acc[1][0], 0, 0, 0);
    acc[1][1] = __builtin_amdgcn_mfma_f32_16x16x32_bf16(a1, b1, acc[1][1], 0, 0, 0);
    __syncthreads();
    if (nxt < kend){ write_lds(); __syncthreads(); }
  }

  float* Pout = P + (size_t)blockIdx.z*M*N;
  #pragma unroll
  for (int t = 0; t < 2; t++)
    #pragma unroll
    for (int u = 0; u < 2; u++)
      #pragma unroll
      for (int j = 0; j < 4; j++){
        int row = bm + wr + t*16 + quad*4 + j;
        int col = bn + wc + u*16 + ln;
        if (col < N) Pout[(size_t)row*N + col] = acc[t][u][j];
      }
}

// ---------------- fused: out = act(LN_last(sum_ks P + bias)); obf: write bf16 ----------------
__global__ __launch_bounds__(256) void reduce_ln(
    const float* __restrict__ Pp, const float* __restrict__ bias,
    void* __restrict__ outp, int M, int N, int KS, int os, int act, int obf, int bmask)
{
  __shared__ float rowbuf[4096];
  __shared__ float sbuf[16];
  int row = blockIdx.x;
  size_t MN = (size_t)M*N;
  float s = 0.f, s2 = 0.f;
  for (int c = threadIdx.x; c < N; c += 256){
    float v = bias[c & bmask];
    for (int ks = 0; ks < KS; ks++) v += Pp[ks*MN + (size_t)row*N + c];
    rowbuf[c] = v; s += v; s2 += v*v;
  }
  block_reduce2(s, s2, sbuf);
  float m = s / N;
  float r = rsqrtf(s2/N - m*m + 1e-5f);
  for (int c = threadIdx.x; c < N; c += 256){
    float v = (rowbuf[c]-m)*r;
    if (act == 1) v = fmaxf(v, 0.f);
    else if (act == 2) v = eluf(v);
    else if (act == 3) v = tanhf(v);
    if (obf) ((short*)outp)[(size_t)row*os + c] = f2bf(v);
    else     ((float*)outp)[(size_t)row*os + c] = v;
  }
}

// ---------------- fused NS: XR bf16, state_out fp32 ----------------
__global__ __launch_bounds__(256) void reduce_ns(
    const float* __restrict__ Pp, const float* __restrict__ bias,
    short* __restrict__ XRb, float* __restrict__ so, int M, int N, int KS)
{
  __shared__ float rowbuf[256];
  __shared__ float sbuf[16];
  int row = blockIdx.x;
  size_t MN = (size_t)M*N;
  float s = 0.f, s2 = 0.f;
  for (int c = threadIdx.x; c < N; c += 256){
    float v = bias[c];
    for (int ks = 0; ks < KS; ks++) v += Pp[ks*MN + (size_t)row*N + c];
    rowbuf[c] = v; s += v; s2 += v*v;
  }
  block_reduce2(s, s2, sbuf);
  float m = s / N;
  float r = rsqrtf(s2/N - m*m + 1e-5f);
  for (int c = threadIdx.x; c < N; c += 256){
    float v = rowbuf[c];
    XRb[(size_t)row*256 + c] = f2bf(sigf((v-m)*r));
    so[(size_t)row*N + c] = sigf(v);
  }
}

// ---------------- ctx/att1 LN + att2 + effect, wave-parallel (7 waves) ----------------
__global__ __launch_bounds__(448) void ctx_att_effect(
    const float* __restrict__ Pc, const float* __restrict__ ctx_b,
    const float* __restrict__ Pa, const float* __restrict__ att1_b,
    const float* __restrict__ w2, const float* __restrict__ b2,
    short* __restrict__ tot)
{
  __shared__ float ctxs[7][250];
  __shared__ float att_s[7];
  int fi = blockIdx.x, tid = threadIdx.x;
  int jj = tid >> 6, lane = tid & 63;
  const size_t MN = (size_t)2688*250, MN2 = (size_t)2688*100;
  int row = fi*7 + jj;
  // ctx: LN + relu
  float vv[4];
  float s = 0.f, s2 = 0.f;
  #pragma unroll
  for (int t = 0; t < 4; t++){
    int c = lane + t*64;
    float v = 0.f;
    if (c < 250) v = ctx_b[c] + Pc[(size_t)row*250 + c] + Pc[MN + (size_t)row*250 + c];
    vv[t] = v; s += v; s2 += v*v;
  }
  #pragma unroll
  for (int off = 32; off; off >>= 1){ s += __shfl_down(s, off); s2 += __shfl_down(s2, off); }
  s = __shfl(s, 0); s2 = __shfl(s2, 0);
  float m = s*(1.f/250.f);
  float r = rsqrtf(s2*(1.f/250.f) - m*m + 1e-5f);
  #pragma unroll
  for (int t = 0; t < 4; t++){
    int c = lane + t*64;
    if (c < 250) ctxs[jj][c] = fmaxf((vv[t]-m)*r, 0.f);
  }
  // att1: LN + tanh + dot(w2) + sigmoid
  float va[2];
  s = 0.f; s2 = 0.f;
  #pragma unroll
  for (int t = 0; t < 2; t++){
    int c = lane + t*64;
    float v = 0.f;
    if (c < 100){
      v = att1_b[c];
      #pragma unroll
      for (int ks = 0; ks < 4; ks++) v += Pa[ks*MN2 + (size_t)row*100 + c];
    }
    va[t] = v; s += v; s2 += v*v;
  }
  #pragma unroll
  for (int off = 32; off; off >>= 1){ s += __shfl_down(s, off); s2 += __shfl_down(s2, off); }
  s = __shfl(s, 0); s2 = __shfl(s2, 0);
  m = s*0.01f;
  r = rsqrtf(s2*0.01f - m*m + 1e-5f);
  float d = 0.f;
  #pragma unroll
  for (int t = 0; t < 2; t++){
    int c = lane + t*64;
    if (c < 100) d += tanhf((va[t]-m)*r)*w2[c];
  }
  #pragma unroll
  for (int off = 32; off; off >>= 1) d += __shfl_down(d, off);
  if (lane == 0) att_s[jj] = sigf(d + b2[0]);
  __syncthreads();
  for (int h = tid; h < 250; h += 448){
    float sum = 0.f;
    #pragma unroll
    for (int q = 0; q < 7; q++) sum += ctxs[q][h]*att_s[q];
    tot[(size_t)fi*1024 + 256 + h] = f2bf(sum);
  }
}

// ---------------- enc_conv1: x(n,64,64) -> FINAL bf16 elu(LN) (n,32,32,16) ----------------
__global__ __launch_bounds__(256) void enc_conv1_ig(
    const float* __restrict__ x, const float* __restrict__ w, const float* __restrict__ bias,
    short* __restrict__ outp)
{
  __shared__ __align__(16) float in_t[66*68];
  __shared__ short rawb[16384];
  __shared__ float sbuf[16];
  int n = blockIdx.x, tid = threadIdx.x;
  for (int l = tid; l < 66*68; l += 256) in_t[l] = 0.f;
  __syncthreads();
  const float* xin = x + (size_t)n*4096;
  for (int l4 = tid; l4 < 1024; l4 += 256){
    float4 v = *(const float4*)&xin[l4*4];
    int aa = (l4*4) >> 6, bb = (l4*4) & 63;
    float* dst = &in_t[(aa+1)*68 + bb + 1];
    dst[0]=v.x; dst[1]=v.y; dst[2]=v.z; dst[3]=v.w;
  }
  int o = tid & 15;
  float wr[16];
  #pragma unroll
  for (int t = 0; t < 16; t++) wr[t] = w[o*16 + t];
  float bv = bias[o];
  __syncthreads();
  float s = 0.f, s2 = 0.f;
  for (int r = 0; r < 64; r++){
    int idx = tid + (r<<8);
    int bq = (idx>>4)&31, aq = idx>>9;
    int a0 = 2*aq, b0 = 2*bq;
    float acc = bv;
    #pragma unroll
    for (int kw = 0; kw < 4; kw++){
      const float* row = &in_t[(a0+kw)*68 + b0];
      float2 p0 = *(const float2*)&row[0];
      float2 p1 = *(const float2*)&row[2];
      acc += p0.x*wr[0*4+kw] + p0.y*wr[1*4+kw] + p1.x*wr[2*4+kw] + p1.y*wr[3*4+kw];
    }
    rawb[idx] = f2bf(acc);
    s += acc; s2 += acc*acc;
  }
  block_reduce2(s, s2, sbuf);
  float m = s*(1.f/16384.f);
  float rs = rsqrtf(s2*(1.f/16384.f) - m*m + 1e-5f);
  short* op = outp + (size_t)n*16384;
  for (int l = tid; l < 16384; l += 256){
    float v = bf2f(rawb[l]);
    op[l] = f2bf(eluf((v-m)*rs));
  }
}

// ---------------- fused dec_conv1+2: G2b final bf16 -> D2b final bf16 (one block/sample) ----------------
__global__ __launch_bounds__(256) void dec_conv12_mfma(
    const short* __restrict__ in, const short* __restrict__ Bd1, const float* __restrict__ bias1,
    const short* __restrict__ Bd2, const float* __restrict__ bias2, short* __restrict__ outp)
{
  __shared__ __align__(16) short smem[18*18*32];   // conv1 staging (10*10*64) then conv2 staging
  __shared__ float sbuf[16];
  int n = blockIdx.x, tid = threadIdx.x;
  for (int l = tid; l < 1600; l += 256) ((unsigned long long*)smem)[l] = 0ull;   // 6400 shorts
  __syncthreads();
  const short* ip = in + (size_t)n*4096;
  for (int l = tid; l < 1024; l += 256){
    int i4 = l & 15, sb = (l>>4)&7, sa = l>>7;
    *(uint2*)&smem[((sa+1)*10 + (sb+1))*64 + i4*4] = *(const uint2*)&ip[sa*512 + sb*64 + i4*4];
  }
  int wave = tid>>6, ln = tid&15, quad = (tid>>4)&3;
  int pa = wave & 1, pb = wave >> 1;
  bf16x8 bfr1[2][8];
  #pragma unroll
  for (int nt = 0; nt < 2; nt++){
    const short* Brow = Bd1 + (wave*32 + nt*16 + ln)*256;
    #pragma unroll
    for (int ks = 0; ks < 8; ks++)
      bfr1[nt][ks] = *(const bf16x8*)&Brow[ks*32 + quad*8];
  }
  __syncthreads();
  f32x4 z = {0.f,0.f,0.f,0.f};
  f32x4 acc[2][4] = {{z,z,z,z},{z,z,z,z}};
  #pragma unroll
  for (int ks = 0; ks < 8; ks++){
    int tap = ks>>1, ibase = (ks&1)*32 + quad*8;
    int da = tap & 1, db = tap >> 1;
    #pragma unroll
    for (int mt = 0; mt < 4; mt++){
      int p = mt*16 + ln;
      int ta = p>>3, tb = p&7;
      bf16x8 a = *(const bf16x8*)&smem[((ta+da+pa)*10 + (tb+db+pb))*64 + ibase];
      acc[0][mt] = __builtin_amdgcn_mfma_f32_16x16x32_bf16(a, bfr1[0][ks], acc[0][mt],0,0,0);
      acc[1][mt] = __builtin_amdgcn_mfma_f32_16x16x32_bf16(a, bfr1[1][ks], acc[1][mt],0,0,0);
    }
  }
  float s = 0.f, s2 = 0.f;
  #pragma unroll
  for (int nt = 0; nt < 2; nt++){
    float bz = bias1[nt*16 + ln];
    #pragma unroll
    for (int mt = 0; mt < 4; mt++)
      #pragma unroll
      for (int j = 0; j < 4; j++){
        float v = acc[nt][mt][j] + bz;
        acc[nt][mt][j] = v; s += v; s2 += v*v;
      }
  }
  block_reduce2(s, s2, sbuf);   // final barrier also guards smem reuse
  float m1 = s*(1.f/8192.f);
  float rs1 = rsqrtf(s2*(1.f/8192.f) - m1*m1 + 1e-5f);
  bf16x8 bfr2[4];
  {
    const short* Brow = Bd2 + (wave*16 + ln)*128;
    #pragma unroll
    for (int ks = 0; ks < 4; ks++)
      bfr2[ks] = *(const bf16x8*)&Brow[ks*32 + quad*8];
  }
  for (int l = tid; l < 2592; l += 256) ((unsigned long long*)smem)[l] = 0ull;   // 10368 shorts
  __syncthreads();
  #pragma unroll
  for (int nt = 0; nt < 2; nt++){
    int o = nt*16 + ln;
    #pragma unroll
    for (int mt = 0; mt < 4; mt++)
      #pragma unroll
      for (int j = 0; j < 4; j++){
        int p = mt*16 + quad*4 + j;
        int ta = p>>3, tb = p&7;
        int sa = 2*ta + pa, sb = 2*tb + pb;
        smem[((sa+1)*18 + (sb+1))*32 + o] = f2bf(fmaxf((acc[nt][mt][j]-m1)*rs1, 0.f));
      }
  }
  __syncthreads();
  f32x4 acc2[16] = {z,z,z,z,z,z,z,z,z,z,z,z,z,z,z,z};
  #pragma unroll
  for (int ks = 0; ks < 4; ks++){
    int da = ks & 1, db = ks >> 1;
    #pragma unroll
    for (int mt = 0; mt < 16; mt++){
      int p = mt*16 + ln;
      int ta = p>>4, tb = p&15;
      bf16x8 a = *(const bf16x8*)&smem[((ta+da+pa)*18 + (tb+db+pb))*32 + quad*8];
      acc2[mt] = __builtin_amdgcn_mfma_f32_16x16x32_bf16(a, bfr2[ks], acc2[mt],0,0,0);
    }
  }
  s = 0.f; s2 = 0.f;
  float bz2 = bias2[ln];
  #pragma unroll
  for (int mt = 0; mt < 16; mt++)
    #pragma unroll
    for (int j = 0; j < 4; j++){
      float v = acc2[mt][j] + bz2;
      acc2[mt][j] = v; s += v; s2 += v*v;
    }
  block_reduce2(s, s2, sbuf);
  float m = s*(1.f/16384.f);
  float rs = rsqrtf(s2*(1.f/16384.f) - m*m + 1e-5f);
  short* op = outp + (size_t)n*16384;
  #pragma unroll
  for (int mt = 0; mt < 16; mt++)
    #pragma unroll
    for (int j = 0; j < 4; j++){
      int p = mt*16 + quad*4 + j;
      int ta = p>>4, tb = p&15;
      op[(2*ta+pa)*512 + (2*tb+pb)*16 + ln] = f2bf(fmaxf((acc2[mt][j]-m)*rs, 0.f));
    }
}

// ---------------- dec_conv3 (final bf16 in) ----------------
__global__ __launch_bounds__(256) void dec_conv3_ig(
    const short* __restrict__ in, const float* __restrict__ CWT, const float* __restrict__ bias,
    float* __restrict__ outp)
{
  __shared__ __align__(16) float in_t[9792];   // [sa34][sb18][i16]
  __shared__ __align__(16) float wl[256];
  int bx = blockIdx.x;
  int n = bx >> 1, b0 = (bx & 1) * 32, tb0 = b0 >> 1;
  int tid = threadIdx.x;
  const short* ip = in + (size_t)n*16384;
  for (int l = tid; l < 9792; l += 256){
    int i = l & 15, sb = (l >> 4) % 18, sap = l / 288;
    int sa = sap - 1, sbg = tb0 - 1 + sb;
    float v = 0.f;
    if ((unsigned)sa < 32u && (unsigned)sbg < 32u)
      v = bf2f(ip[sa*512 + sbg*16 + i]);
    in_t[(sap*18 + sb)*16 + i] = v;
  }
  for (int l = tid; l < 256; l += 256) wl[l] = CWT[l];
  __syncthreads();
  float bv = bias[0];
  int bl = tid & 31, ath = tid >> 5;
  int b = b0 + bl;
  int tb = b >> 1, pb = b & 1;
  float* op = outp + (size_t)n*4096;
  #pragma unroll
  for (int j = 0; j < 8; j++){
    int a = ath*8 + j;
    int ta = a >> 1, pa = a & 1;
    float4 s4 = make_float4(0.f,0.f,0.f,0.f);
    #pragma unroll
    for (int db = 0; db < 2; db++){
      int sb = tb + db + (pb ? 0 : -1);
      int sbl = sb - (tb0 - 1);
      #pragma unroll
      for (int da = 0; da < 2; da++){
        int sa = ta + da + (pa ? 0 : -1);
        int sap = sa + 1;
        const float4* A4 = (const float4*)&in_t[(sap*18 + sbl)*16];
        const float4* B4 = (const float4*)&wl[((pb*2+pa)*4 + db*2+da)*16];
        #pragma unroll
        for (int q = 0; q < 4; q++){
          float4 av = A4[q], bw = B4[q];
          s4.x += av.x*bw.x; s4.y += av.y*bw.y;
          s4.z += av.z*bw.z; s4.w += av.w*bw.w;
        }
      }
    }
    op[a*64 + b] = sigf(bv + s4.x + s4.y + s4.z + s4.w);
  }
}

extern "C" void kernel_launch(void* const* d_in, const int* in_sizes, int n_in,
                              void* d_out, int out_size, void* d_ws, size_t ws_size,
                              hipStream_t stream) {
  const float* x      = (const float*)d_in[0];
  const float* state  = (const float*)d_in[1];
  const float* c1w    = (const float*)d_in[2];
  const float* c1b    = (const float*)d_in[3];
  const float* c2w    = (const float*)d_in[4];
  const float* c2b    = (const float*)d_in[5];
  const float* c3w    = (const float*)d_in[6];
  const float* c3b    = (const float*)d_in[7];
  const float* efc_w  = (const float*)d_in[8];
  const float* efc_b  = (const float*)d_in[9];
  const float* renc_w = (const float*)d_in[10];
  const float* renc_b = (const float*)d_in[11];
  const float* core_w = (const float*)d_in[12];
  const float* core_b = (const float*)d_in[13];
  const float* ctx_w  = (const float*)d_in[14];
  const float* ctx_b  = (const float*)d_in[15];
  const float* att1_w = (const float*)d_in[16];
  const float* att1_b = (const float*)d_in[17];
  const float* att2_w = (const float*)d_in[18];
  const float* att2_b = (const float*)d_in[19];
  const float* out_w  = (const float*)d_in[20];
  const float* out_b  = (const float*)d_in[21];
  const float* dfc1_w = (const float*)d_in[22];
  const float* dfc1_b = (const float*)d_in[23];
  const float* dfc2_w = (const float*)d_in[24];
  const float* dfc2_b = (const float*)d_in[25];
  const float* d1w    = (const float*)d_in[26];
  const float* d1b    = (const float*)d_in[27];
  const float* d2w    = (const float*)d_in[28];
  const float* d2b    = (const float*)d_in[29];
  const float* d3w    = (const float*)d_in[30];
  const float* d3b    = (const float*)d_in[31];

  float* wsf = (float*)d_ws;
  size_t o = 0;
  float* PB   = wsf + o; o += (size_t)1600*1024;    // split-K partials (fp32)
  float* PB2  = wsf + o; o += (size_t)2688*100*4;   // att1 partials (KS=4)
  float* CWT3 = wsf + o; o += 256;
  // bf16 buffers (sizes in shorts; offsets in floats)
  short* E1b  = (short*)(wsf + o); o += (size_t)384*16384/2;   // enc1 final; later dec2 final
  short* E2b  = (short*)(wsf + o); o += (size_t)384*8192/2;    // conv2 raw->activated bf16
  short* E3b  = (short*)(wsf + o); o += (size_t)384*4096/2;    // enc3 final; later G2 final
  short* TOTb = (short*)(wsf + o); o += (size_t)384*1024/2;    // [s1|pad|eff|pad|h]
  short* C1b  = (short*)(wsf + o); o += (size_t)2688*256/2;
  short* XRb  = (short*)(wsf + o); o += (size_t)384*256/2;
  short* G1b  = (short*)(wsf + o); o += (size_t)384*512/2;
  short* SBF  = (short*)(wsf + o); o += (size_t)384*256/2;
  short* BtC2 = (short*)(wsf + o); o += 8192/2;
  short* BtC3 = (short*)(wsf + o); o += 32768/2;
  short* BD1  = (short*)(wsf + o); o += 32768/2;
  short* BD2  = (short*)(wsf + o); o += 8192/2;
  short* BT_efc  = (short*)(wsf + o); o += 2097152/2;
  short* BT_renc = (short*)(wsf + o); o += 64000/2;
  short* BT_core = (short*)(wsf + o); o += 128000/2;
  short* BT_ctx  = (short*)(wsf + o); o += 64000/2;
  short* BT_att1 = (short*)(wsf + o); o += 25600/2;
  short* BT_out  = (short*)(wsf + o); o += 256000/2;
  short* BT_dfc1 = (short*)(wsf + o); o += 131072/2;
  short* BT_dfc2 = (short*)(wsf + o); o += 2097152/2;
  short* D2b = E1b;
  short* G2b = E3b;

  float* xout = (float*)d_out;
  float* sout = xout + (size_t)384*4096;

  // one prep kernel: weight transposes + folds + state cvt + TOT pad zero
  prep_combined<<<1448, 256, 0, stream>>>(
      efc_w, BT_efc, dfc2_w, BT_dfc2, out_w, BT_out, core_w, BT_core,
      dfc1_w, BT_dfc1, renc_w, BT_renc, ctx_w, BT_ctx, att1_w, BT_att1,
      d3w, CWT3, c2w, BtC2, c3w, BtC3, d1w, BD1, d2w, BD2, state, SBF, TOTb);

  // encoder: conv1, then conv2/conv3 as gather-GEMMs + per-sample LN
  enc_conv1_ig<<<384, 256, 0, stream>>>(x, c1w, c1b, E1b);
  gemm_conv2g<<<768, 256, 0, stream>>>(E1b, BtC2, E2b);
  ln_conv2_act<<<384, 256, 0, stream>>>(E2b, c2b);
  gemm_conv3g<<<384, 256, 0, stream>>>(E2b, BtC3, PB);
  reduce_ln<<<384, 256, 0, stream>>>(PB, c3b, E3b, 384, 4096, 1, 4096, 2, 1, 63);
  gemm_mfma<<<dim3(8,6,8), 256, 0, stream>>>(E3b, BT_efc, PB, 384, 512, 4096, 512);
  reduce_ln<<<384, 256, 0, stream>>>(PB, efc_b, TOTb+512, 384, 512, 8, 1024, 2, 1, -1);

  // state path
  gemm_mfma<<<dim3(4,6,8), 256, 0, stream>>>(SBF, BT_renc, PB, 384, 250, 256, 32);
  reduce_ln<<<384, 256, 0, stream>>>(PB, renc_b, TOTb, 384, 250, 8, 1024, 1, 1, -1);
  gemm_core_mfma<<<dim3(4,42,2), 256, 0, stream>>>(TOTb, BT_core, PB, 2688, 250, 256);
  reduce_ln<<<2688, 256, 0, stream>>>(PB, core_b, C1b, 2688, 250, 2, 256, 1, 1, -1);
  gemm_mfma<<<dim3(4,42,2), 256, 0, stream>>>(C1b, BT_ctx, PB, 2688, 250, 256, 128);
  gemm_mfma<<<dim3(2,42,4), 256, 0, stream>>>(C1b, BT_att1, PB2, 2688, 100, 256, 64);
  ctx_att_effect<<<384, 448, 0, stream>>>(PB, ctx_b, PB2, att1_b, att2_w, att2_b, TOTb);

  // combine
  gemm_mfma<<<dim3(4,6,8), 256, 0, stream>>>(TOTb, BT_out, PB, 384, 250, 1024, 128);
  reduce_ns<<<384, 256, 0, stream>>>(PB, out_b, XRb, sout, 384, 250, 8);

  // decoder FC
  gemm_mfma<<<dim3(8,6,4), 256, 0, stream>>>(XRb, BT_dfc1, PB, 384, 512, 256, 64);
  reduce_ln<<<384, 256, 0, stream>>>(PB, dfc1_b, G1b, 384, 512, 4, 512, 1, 1, -1);
  gemm_mfma<<<dim3(64,6,1), 256, 0, stream>>>(G1b, BT_dfc2, PB, 384, 4096, 512, 512);
  reduce_ln<<<384, 256, 0, stream>>>(PB, dfc2_b, G2b, 384, 4096, 1, 4096, 1, 1, -1);

  // decoder convs (fused conv1+2, then conv3)
  dec_conv12_mfma<<<384, 256, 0, stream>>>(G2b, BD1, d1b, BD2, d2b, D2b);
  dec_conv3_ig<<<768, 256, 0, stream>>>(D2b, CWT3, d3b, xout);

  (void)in_sizes; (void)n_in; (void)out_size; (void)ws_size;
}

// Round 5
// 322.339 us; speedup vs baseline: 1.0539x; 1.0539x over previous
//
#include <hip/hip_runtime.h>
#include <hip/hip_bf16.h>
#include <math.h>

typedef __attribute__((ext_vector_type(8))) short bf16x8;
typedef __attribute__((ext_vector_type(4))) float f32x4;

__device__ __forceinline__ float eluf(float v){ return v > 0.f ? v : expm1f(v); }
__device__ __forceinline__ float sigf(float v){ return 1.f/(1.f+expf(-v)); }
__device__ __forceinline__ unsigned short f2bf(float f){
  unsigned u = __float_as_uint(f);
  u += 0x7FFFu + ((u >> 16) & 1u);          // round-to-nearest-even
  return (unsigned short)(u >> 16);
}
__device__ __forceinline__ float bf2f(short s){
  return __uint_as_float(((unsigned)(unsigned short)s) << 16);
}

// ---------------- block-wide sum & sumsq reduction ----------------
__device__ __forceinline__ void block_reduce2(float& a, float& b, float* sbuf){
  __syncthreads();
  for (int off = 32; off; off >>= 1){
    a += __shfl_down(a, off);
    b += __shfl_down(b, off);
  }
  int lane = threadIdx.x & 63, w = threadIdx.x >> 6;
  if (lane == 0){ sbuf[2*w] = a; sbuf[2*w+1] = b; }
  __syncthreads();
  if (threadIdx.x == 0){
    int nw = blockDim.x >> 6;
    float sa = 0.f, sb = 0.f;
    for (int i = 0; i < nw; i++){ sa += sbuf[2*i]; sb += sbuf[2*i+1]; }
    sbuf[0] = sa; sbuf[1] = sb;
  }
  __syncthreads();
  a = sbuf[0]; b = sbuf[1];
}

// ---------------- prep helpers ----------------
__device__ __forceinline__ float fold_sum(const float* __restrict__ w, int O, int I,
                                          int o, int i, int pa, int pb, int da, int db){
  float s = 0.f;
  for (int kh = 0; kh < 4; kh++){
    bool inh = (pb==0) ? (db==0 ? (kh==0) : (kh>=1)) : (db==0 ? (kh<=2) : (kh==3));
    if (!inh) continue;
    for (int kw = 0; kw < 4; kw++){
      bool inw = (pa==0) ? (da==0 ? (kw==0) : (kw>=1)) : (da==0 ? (kw<=2) : (kw==3));
      if (!inw) continue;
      s += w[((o*I + i)*4 + kh)*4 + kw];
    }
  }
  return s;
}
__device__ __forceinline__ void fold_elem(const float* __restrict__ w, float* __restrict__ CW,
                                          int O, int I, int l){
  int o = l % O; int q = l / O;
  int da = q & 1, db = (q>>1)&1, pa = (q>>2)&1, pb = (q>>3)&1, i = q>>4;
  CW[(((pb*2+pa)*4 + db*2+da)*I + i)*O + o] = fold_sum(w, O, I, o, i, pa, pb, da, db);
}
__device__ __forceinline__ void cvtc2_elem(const float* __restrict__ w, short* __restrict__ D, int l){
  int i = l & 15, t = (l>>4) & 15, o = l>>8;        // k = t*16 + i
  D[l] = (short)f2bf(w[(o*16 + i)*16 + t]);
}
__device__ __forceinline__ void cvtc3_elem(const float* __restrict__ w, short* __restrict__ D, int l){
  int i = l & 31, t = (l>>5) & 15, o = l>>9;        // k = t*32 + i
  D[l] = (short)f2bf(w[(o*32 + i)*16 + t]);
}
__device__ __forceinline__ void foldd1_elem(const float* __restrict__ w, short* __restrict__ D, int l){
  int i = l & 63, tap = (l>>6)&3, o = (l>>8)&31, ph = l>>13;
  D[l] = (short)f2bf(fold_sum(w, 32, 64, o, i, ph&1, ph>>1, tap&1, tap>>1));
}
__device__ __forceinline__ void foldd2_elem(const float* __restrict__ w, short* __restrict__ D, int l){
  int i = l & 31, tap = (l>>5)&3, o = (l>>7)&15, ph = l>>11;
  D[l] = (short)f2bf(fold_sum(w, 16, 32, o, i, ph&1, ph>>1, tap&1, tap>>1));
}

// ---------------- combined prep: weight transposes (blocks 0..1191) + small packs ----------------
__global__ __launch_bounds__(256) void prep_combined(
  const float* __restrict__ efc,  short* __restrict__ Defc,
  const float* __restrict__ dfc2, short* __restrict__ Ddfc2,
  const float* __restrict__ outw, short* __restrict__ Dout,
  const float* __restrict__ corew,short* __restrict__ Dcore,
  const float* __restrict__ dfc1, short* __restrict__ Ddfc1,
  const float* __restrict__ renc, short* __restrict__ Drenc,
  const float* __restrict__ ctx,  const float* __restrict__ att1,
  short* __restrict__ Dctxatt,
  const float* __restrict__ d3w, float* __restrict__ CWT3,
  const float* __restrict__ c2w, short* __restrict__ BtC2,
  const float* __restrict__ c3w, short* __restrict__ BtC3,
  const float* __restrict__ d1w, short* __restrict__ BD1,
  const float* __restrict__ d2w, short* __restrict__ BD2,
  const float* __restrict__ state, short* __restrict__ SBF,
  short* __restrict__ TOTb)
{
  int bx = blockIdx.x;
  if (bx >= 1192){
    const int F3=256, P2=F3+8192, P3=P2+32768, P4=P3+32768, P5=P4+8192,
              ST=P5+98304, TP=ST+4608, TOTAL=TP+8704;
    for (int l = (bx-1192)*256 + threadIdx.x; l < TOTAL; l += 256*256){
      if (l < F3)      fold_elem(d3w, CWT3, 1, 16, l);
      else if (l < P2) cvtc2_elem(c2w, BtC2, l - F3);
      else if (l < P3) cvtc3_elem(c3w, BtC3, l - P2);
      else if (l < P4) foldd1_elem(d1w, BD1, l - P3);
      else if (l < P5) foldd2_elem(d2w, BD2, l - P4);
      else if (l < ST){
        int q = l - P5;             // state -> bf16 [384][256], zero pad
        int n = q >> 8, k = q & 255;
        SBF[q] = (k < 250) ? (short)f2bf(state[n*250 + k]) : (short)0;
      } else if (l < TP){
        int q = l - ST;             // zero TOT pad cols: 250..255, 506..511
        int row = q / 12, cc = q % 12;
        int col = cc < 6 ? 250 + cc : 506 + (cc - 6);
        TOTb[row*1024 + col] = 0;
      } else {
        int q = l - TP;             // zero ctxatt pad rows: 250..255, 356..383
        int r = q >> 8, cc = q & 255;
        int row = r < 6 ? 250 + r : 356 + (r - 6);
        Dctxatt[row*256 + cc] = 0;
      }
    }
    return;
  }
  const float* W; short* D; int K, N, Kp, base, mode = 0;
  if      (bx < 512) { W=efc;  D=Defc;  K=4096; N=512;  Kp=4096; base=0;    }
  else if (bx < 1024){ W=dfc2; D=Ddfc2; K=512;  N=4096; Kp=512;  base=512;  }
  else if (bx < 1088){ W=outw; D=Dout;  K=1012; N=250;  Kp=1024; base=1024; mode=2; }
  else if (bx < 1120){ W=corew;D=Dcore; K=500;  N=250;  Kp=512;  base=1088; mode=1; }
  else if (bx < 1152){ W=dfc1; D=Ddfc1; K=250;  N=512;  Kp=256;  base=1120; }
  else if (bx < 1168){ W=renc; D=Drenc; K=250;  N=250;  Kp=256;  base=1152; }
  else if (bx < 1184){ W=ctx;  D=Dctxatt;         K=250; N=250; Kp=256; base=1168; }
  else               { W=att1; D=Dctxatt + 65536; K=250; N=100; Kp=256; base=1184; }
  int t = bx - base;
  int tpr = Kp >> 6;
  int tk = t % tpr, tn = t / tpr;
  __shared__ short tile[64][65];
  int c = threadIdx.x & 63, r4 = threadIdx.x >> 6;
  int n0 = tn*64, k0 = tk*64;
  #pragma unroll 4
  for (int p = 0; p < 16; p++){
    int r = r4*16 + p;
    int k = k0 + r, n = n0 + c;
    int ksrc = k; bool valid;
    if (mode == 0) valid = (k < K);
    else if (mode == 1){ valid = (k < 250) || (k >= 256 && k < 506); ksrc = k < 256 ? k : k - 6; }
    else { valid = (k < 250) || (k >= 256 && k < 506) || (k >= 512);
           ksrc = k < 256 ? k : (k < 512 ? k - 6 : k - 12); }
    float v = (valid && n < N) ? W[(size_t)ksrc*N + n] : 0.f;
    tile[c][r] = (short)f2bf(v);
  }
  __syncthreads();
  #pragma unroll 4
  for (int p = 0; p < 16; p++){
    int nn = r4*16 + p;
    int n = n0 + nn;
    if (n < N) D[(size_t)n*Kp + k0 + c] = tile[nn][c];
  }
}

// ---------------- MFMA bf16 split-K GEMM, bf16 A ----------------
__global__ __launch_bounds__(256) void gemm_mfma(
    const short* __restrict__ Ab, const short* __restrict__ Bt,
    float* __restrict__ P, int M, int N, int Kp, int Kc)
{
  __shared__ __align__(16) short As[64*32];
  __shared__ __align__(16) short Bs[64*32];
  int tid = threadIdx.x;
  int bm = blockIdx.y*64, bn = blockIdx.x*64;
  int kb = blockIdx.z * Kc;
  int kend = kb + Kc;

  int r = tid >> 2, c = tid & 3;
  const short* Arow = Ab + (size_t)(bm + r)*Kp;
  int gn = bn + r;
  bool bval = gn < N;
  const short* Brow = Bt + (size_t)gn*Kp;

  uint4 hA, hB;
  auto load_regs = [&](int k0){
    hA = *(const uint4*)&Arow[k0 + c*8];
    hB = bval ? *(const uint4*)&Brow[k0 + c*8] : make_uint4(0,0,0,0);
  };
  auto write_lds = [&](){
    *(uint4*)&As[r*32 + c*8] = hA;
    *(uint4*)&Bs[r*32 + c*8] = hB;
  };

  int wave = tid >> 6;
  int ln = tid & 15, quad = (tid >> 4) & 3;
  int wr = (wave >> 1) * 32, wc = (wave & 1) * 32;

  f32x4 zero = {0.f, 0.f, 0.f, 0.f};
  f32x4 acc[2][2] = {{zero, zero}, {zero, zero}};

  load_regs(kb);
  write_lds();
  __syncthreads();
  for (int k0 = kb; k0 < kend; k0 += 32){
    int nxt = k0 + 32;
    if (nxt < kend) load_regs(nxt);
    bf16x8 a0 = *(const bf16x8*)&As[(wr +      ln)*32 + quad*8];
    bf16x8 a1 = *(const bf16x8*)&As[(wr + 16 + ln)*32 + quad*8];
    bf16x8 b0 = *(const bf16x8*)&Bs[(wc +      ln)*32 + quad*8];
    bf16x8 b1 = *(const bf16x8*)&Bs[(wc + 16 + ln)*32 + quad*8];
    acc[0][0] = __builtin_amdgcn_mfma_f32_16x16x32_bf16(a0, b0, acc[0][0], 0, 0, 0);
    acc[0][1] = __builtin_amdgcn_mfma_f32_16x16x32_bf16(a0, b1, acc[0][1], 0, 0, 0);
    acc[1][0] = __builtin_amdgcn_mfma_f32_16x16x32_bf16(a1, b0, acc[1][0], 0, 0, 0);
    acc[1][1] = __builtin_amdgcn_mfma_f32_16x16x32_bf16(a1, b1, acc[1][1], 0, 0, 0);
    __syncthreads();
    if (nxt < kend){ write_lds(); __syncthreads(); }
  }

  float* Pout = P + (size_t)blockIdx.z*M*N;
  #pragma unroll
  for (int t = 0; t < 2; t++)
    #pragma unroll
    for (int u = 0; u < 2; u++)
      #pragma unroll
      for (int j = 0; j < 4; j++){
        int row = bm + wr + t*16 + quad*4 + j;
        int col = bn + wc + u*16 + ln;
        if (col < N) Pout[(size_t)row*N + col] = acc[t][u][j];
      }
}

// ---------------- conv2 as gather-GEMM: A im2col'd from E1b on the fly ----------------
// M = 384*256 rows (n,pos), N = 32 ch, K = 256 (tap16 x ch16). Tile 128x32, grid M/128 = 768.
// Out: raw conv2 (pre-bias, pre-LN) bf16 at [(n*256+pos)*32 + ch]  (= (n, a, b, ch) layout).
__global__ __launch_bounds__(256) void gemm_conv2g(
    const short* __restrict__ In, const short* __restrict__ Bt,
    short* __restrict__ Out)
{
  __shared__ __align__(16) short As[128*32];
  __shared__ __align__(16) short Bs[32*32];
  int tid = threadIdx.x;
  int bm = blockIdx.x*128;

  // A staging: 128 rows, 2x uint4 per thread
  int ra = tid >> 1, ca = (tid & 1)*16;
  int gr = bm + ra;
  int n = gr >> 8, pos = gr & 255;
  int oa = pos >> 4, ob = pos & 15;
  const short* ibase = In + (size_t)n*16384;
  // B staging: first 128 threads, 32 rows x 4 uint4
  int rb = tid >> 2, cb = (tid & 3)*8;
  const short* Brow = Bt + rb*256;
  bool bact = tid < 128;

  uint4 hA0, hA1, hB;
  auto load_regs = [&](int k0){
    #pragma unroll
    for (int h = 0; h < 2; h++){
      int k = k0 + ca + h*8;
      int tap = k >> 4;
      int ai = 2*oa + (tap & 3) - 1, bi = 2*ob + (tap >> 2) - 1;
      bool v = ((unsigned)ai < 32u) && ((unsigned)bi < 32u);
      uint4 tv = v ? *(const uint4*)&ibase[ai*512 + bi*16 + (k & 15)] : make_uint4(0,0,0,0);
      if (h == 0) hA0 = tv; else hA1 = tv;
    }
    if (bact) hB = *(const uint4*)&Brow[k0 + cb];
  };
  auto write_lds = [&](){
    *(uint4*)&As[ra*32 + ca] = hA0;
    *(uint4*)&As[ra*32 + ca + 8] = hA1;
    if (bact) *(uint4*)&Bs[rb*32 + cb] = hB;
  };

  int wave = tid >> 6, ln = tid & 15, quad = (tid >> 4) & 3;
  int wr = wave * 32;

  f32x4 zero = {0.f,0.f,0.f,0.f};
  f32x4 acc[2][2] = {{zero,zero},{zero,zero}};
  load_regs(0); write_lds(); __syncthreads();
  for (int k0 = 0; k0 < 256; k0 += 32){
    int nxt = k0 + 32;
    if (nxt < 256) load_regs(nxt);
    bf16x8 a0 = *(const bf16x8*)&As[(wr +      ln)*32 + quad*8];
    bf16x8 a1 = *(const bf16x8*)&As[(wr + 16 + ln)*32 + quad*8];
    bf16x8 b0 = *(const bf16x8*)&Bs[(     ln)*32 + quad*8];
    bf16x8 b1 = *(const bf16x8*)&Bs[(16 + ln)*32 + quad*8];
    acc[0][0] = __builtin_amdgcn_mfma_f32_16x16x32_bf16(a0, b0, acc[0][0], 0, 0, 0);
    acc[0][1] = __builtin_amdgcn_mfma_f32_16x16x32_bf16(a0, b1, acc[0][1], 0, 0, 0);
    acc[1][0] = __builtin_amdgcn_mfma_f32_16x16x32_bf16(a1, b0, acc[1][0], 0, 0, 0);
    acc[1][1] = __builtin_amdgcn_mfma_f32_16x16x32_bf16(a1, b1, acc[1][1], 0, 0, 0);
    __syncthreads();
    if (nxt < 256){ write_lds(); __syncthreads(); }
  }
  #pragma unroll
  for (int t = 0; t < 2; t++)
    #pragma unroll
    for (int u = 0; u < 2; u++)
      #pragma unroll
      for (int j = 0; j < 4; j++){
        int row = bm + wr + t*16 + quad*4 + j;
        int col = u*16 + ln;
        Out[(size_t)row*32 + col] = (short)f2bf(acc[t][u][j]);
      }
}

// ---------------- fused enc conv3: LN2+ELU (from raw conv2) + conv3 MFMA + LN3+ELU ----------------
// One block per sample. LDS sample tile padded to 40-short slot stride (bank-conflict fix).
__global__ __launch_bounds__(256) void enc_conv3_full(
    const short* __restrict__ E2raw, const float* __restrict__ bias2,
    const short* __restrict__ Bt3, const float* __restrict__ bias3,
    short* __restrict__ outp)
{
  __shared__ __align__(16) short lsamp[18*18*40];   // [18x18 spatial ring][40ch padded]
  __shared__ float sbuf[16];
  int n = blockIdx.x, tid = threadIdx.x;
  const short* ip = E2raw + (size_t)n*8192;
  // 1. load raw conv2 + bias, LN stats over 8192
  float vv[32];
  float s = 0.f, s2 = 0.f;
  #pragma unroll
  for (int t = 0; t < 4; t++){
    bf16x8 v8 = *(const bf16x8*)&ip[(t*256 + tid)*8];
    #pragma unroll
    for (int j = 0; j < 8; j++){
      int e = (t*256 + tid)*8 + j;
      float v = bf2f(v8[j]) + bias2[e & 31];
      vv[t*8+j] = v; s += v; s2 += v*v;
    }
  }
  block_reduce2(s, s2, sbuf);
  float m2 = s*(1.f/8192.f);
  float rs2 = rsqrtf(s2*(1.f/8192.f) - m2*m2 + 1e-5f);
  // 2. zero LDS (ring), write activated interior
  for (int l = tid; l < 18*18*40/4; l += 256) ((unsigned long long*)lsamp)[l] = 0ull;
  __syncthreads();
  #pragma unroll
  for (int t = 0; t < 4; t++){
    int e0 = (t*256 + tid)*8;
    int slot = e0 >> 5, ch0 = e0 & 31;
    int a = slot >> 4, b = slot & 15;
    bf16x8 o8;
    #pragma unroll
    for (int j = 0; j < 8; j++)
      o8[j] = (short)f2bf(eluf((vv[t*8+j]-m2)*rs2));
    *(bf16x8*)&lsamp[((a+1)*18 + (b+1))*40 + ch0] = o8;
  }
  // 3. B frags (global, no LDS dep)
  int wave = tid>>6, ln = tid&15, quad = (tid>>4)&3;
  int o3 = wave*16 + ln;
  bf16x8 bfr3[16];
  {
    const short* Brow = Bt3 + o3*512;
    #pragma unroll
    for (int ks = 0; ks < 16; ks++)
      bfr3[ks] = *(const bf16x8*)&Brow[ks*32 + quad*8];
  }
  __syncthreads();
  f32x4 z = {0.f,0.f,0.f,0.f};
  f32x4 acc3[4] = {z,z,z,z};
  #pragma unroll
  for (int ks = 0; ks < 16; ks++){
    int kh = ks>>2, kw = ks&3;
    #pragma unroll
    for (int mt = 0; mt < 4; mt++){
      int p = mt*16 + ln;
      int oa = p>>3, ob = p&7;
      bf16x8 a = *(const bf16x8*)&lsamp[((2*oa+kw)*18 + (2*ob+kh))*40 + quad*8];
      acc3[mt] = __builtin_amdgcn_mfma_f32_16x16x32_bf16(a, bfr3[ks], acc3[mt],0,0,0);
    }
  }
  s = 0.f; s2 = 0.f;
  float bz3 = bias3[o3];
  #pragma unroll
  for (int mt = 0; mt < 4; mt++)
    #pragma unroll
    for (int j = 0; j < 4; j++){
      float v = acc3[mt][j] + bz3;
      acc3[mt][j] = v; s += v; s2 += v*v;
    }
  block_reduce2(s, s2, sbuf);
  float m3 = s*(1.f/4096.f);
  float rs3 = rsqrtf(s2*(1.f/4096.f) - m3*m3 + 1e-5f);
  short* op = outp + (size_t)n*4096;
  #pragma unroll
  for (int mt = 0; mt < 4; mt++)
    #pragma unroll
    for (int j = 0; j < 4; j++){
      int p = mt*16 + quad*4 + j;
      int oa = p>>3, ob = p&7;
      op[oa*512 + ob*64 + o3] = f2bf(eluf((acc3[mt][j]-m3)*rs3));
    }
}

// ---------------- core GEMM: A gathered from padded TOT (pair fusion) ----------------
__global__ __launch_bounds__(256) void gemm_core_mfma(
    const short* __restrict__ Tb, const short* __restrict__ Bt,
    float* __restrict__ P, int M, int N, int Kc)
{
  __shared__ __align__(16) short As[64*32];
  __shared__ __align__(16) short Bs[64*32];
  int tid = threadIdx.x;
  int bm = blockIdx.y*64, bn = blockIdx.x*64;
  int kb = blockIdx.z * Kc;
  int kend = kb + Kc;

  int r = tid >> 2, c = tid & 3;
  int gr = bm + r;
  int jj2 = gr % 7, fi2 = gr / 7;
  int ii = fi2 & 7, j2 = fi2 >> 3;
  int jidx = jj2 < ii ? jj2 : jj2 + 1;
  const short* own = Tb + (size_t)fi2*1024;
  const short* oth = Tb + (size_t)(j2*8 + jidx)*1024;
  int gn = bn + r;
  bool bval = gn < N;
  const short* Brow = Bt + (size_t)gn*512;

  uint4 hA, hB;
  auto load_regs = [&](int k0){
    int kk = k0 + c*8;
    const short* src = (kk & 256) ? oth : own;
    hA = *(const uint4*)&src[kk & 255];
    hB = bval ? *(const uint4*)&Brow[kk] : make_uint4(0,0,0,0);
  };
  auto write_lds = [&](){
    *(uint4*)&As[r*32 + c*8] = hA;
    *(uint4*)&Bs[r*32 + c*8] = hB;
  };

  int wave = tid >> 6;
  int ln = tid & 15, quad = (tid >> 4) & 3;
  int wr = (wave >> 1) * 32, wc = (wave & 1) * 32;

  f32x4 zero = {0.f, 0.f, 0.f, 0.f};
  f32x4 acc[2][2] = {{zero, zero}, {zero, zero}};

  load_regs(kb);
  write_lds();
  __syncthreads();
  for (int k0 = kb; k0 < kend; k0 += 32){
    int nxt = k0 + 32;
    if (nxt < kend) load_regs(nxt);
    bf16x8 a0 = *(const bf16x8*)&As[(wr +      ln)*32 + quad*8];
    bf16x8 a1 = *(const bf16x8*)&As[(wr + 16 + ln)*32 + quad*8];
    bf16x8 b0 = *(const bf16x8*)&Bs[(wc +      ln)*32 + quad*8];
    bf16x8 b1 = *(const bf16x8*)&Bs[(wc + 16 + ln)*32 + quad*8];
    acc[0][0] = __builtin_amdgcn_mfma_f32_16x16x32_bf16(a0, b0, acc[0][0], 0, 0, 0);
    acc[0][1] = __builtin_amdgcn_mfma_f32_16x16x32_bf16(a0, b1, acc[0][1], 0, 0, 0);
    acc[1][0] = __builtin_amdgcn_mfma_f32_16x16x32_bf16(a1, b0, acc[1][0], 0, 0, 0);
    acc[1][1] = __builtin_amdgcn_mfma_f32_16x16x32_bf16(a1, b1, acc[1][1], 0, 0, 0);
    __syncthreads();
    if (nxt < kend){ write_lds(); __syncthreads(); }
  }

  float* Pout = P + (size_t)blockIdx.z*M*N;
  #pragma unroll
  for (int t = 0; t < 2; t++)
    #pragma unroll
    for (int u = 0; u < 2; u++)
      #pragma unroll
      for (int j = 0; j < 4; j++){
        int row = bm + wr + t*16 + quad*4 + j;
        int col = bn + wc + u*16 + ln;
        if (col < N) Pout[(size_t)row*N + col] = acc[t][u][j];
      }
}

// ---------------- fused: out = act(LN_last(sum_ks P + bias)); obf: write bf16 ----------------
__global__ __launch_bounds__(256) void reduce_ln(
    const float* __restrict__ Pp, const float* __restrict__ bias,
    void* __restrict__ outp, int M, int N, int KS, int os, int act, int obf, int bmask)
{
  __shared__ float rowbuf[4096];
  __shared__ float sbuf[16];
  int row = blockIdx.x;
  size_t MN = (size_t)M*N;
  float s = 0.f, s2 = 0.f;
  for (int c = threadIdx.x; c < N; c += 256){
    float v = bias[c & bmask];
    for (int ks = 0; ks < KS; ks++) v += Pp[ks*MN + (size_t)row*N + c];
    rowbuf[c] = v; s += v; s2 += v*v;
  }
  block_reduce2(s, s2, sbuf);
  float m = s / N;
  float r = rsqrtf(s2/N - m*m + 1e-5f);
  for (int c = threadIdx.x; c < N; c += 256){
    float v = (rowbuf[c]-m)*r;
    if (act == 1) v = fmaxf(v, 0.f);
    else if (act == 2) v = eluf(v);
    else if (act == 3) v = tanhf(v);
    if (obf) ((short*)outp)[(size_t)row*os + c] = f2bf(v);
    else     ((float*)outp)[(size_t)row*os + c] = v;
  }
}

// ---------------- fused NS: XR bf16, state_out fp32 ----------------
__global__ __launch_bounds__(256) void reduce_ns(
    const float* __restrict__ Pp, const float* __restrict__ bias,
    short* __restrict__ XRb, float* __restrict__ so, int M, int N, int KS)
{
  __shared__ float rowbuf[256];
  __shared__ float sbuf[16];
  int row = blockIdx.x;
  size_t MN = (size_t)M*N;
  float s = 0.f, s2 = 0.f;
  for (int c = threadIdx.x; c < N; c += 256){
    float v = bias[c];
    for (int ks = 0; ks < KS; ks++) v += Pp[ks*MN + (size_t)row*N + c];
    rowbuf[c] = v; s += v; s2 += v*v;
  }
  block_reduce2(s, s2, sbuf);
  float m = s / N;
  float r = rsqrtf(s2/N - m*m + 1e-5f);
  for (int c = threadIdx.x; c < N; c += 256){
    float v = rowbuf[c];
    XRb[(size_t)row*256 + c] = f2bf(sigf((v-m)*r));
    so[(size_t)row*N + c] = sigf(v);
  }
}

// ---------------- ctx/att1 LN + att2 + effect; reads fused P [2688][384] x 2 slices ----------------
__global__ __launch_bounds__(448) void ctx_att_effect(
    const float* __restrict__ Pc, const float* __restrict__ ctx_b,
    const float* __restrict__ att1_b,
    const float* __restrict__ w2, const float* __restrict__ b2,
    short* __restrict__ tot)
{
  __shared__ float ctxs[7][250];
  __shared__ float att_s[7];
  int fi = blockIdx.x, tid = threadIdx.x;
  int jj = tid >> 6, lane = tid & 63;
  const size_t MN = (size_t)2688*384;
  int row = fi*7 + jj;
  // ctx: LN + relu (cols 0..249)
  float vv[4];
  float s = 0.f, s2 = 0.f;
  #pragma unroll
  for (int t = 0; t < 4; t++){
    int c = lane + t*64;
    float v = 0.f;
    if (c < 250) v = ctx_b[c] + Pc[(size_t)row*384 + c] + Pc[MN + (size_t)row*384 + c];
    vv[t] = v; s += v; s2 += v*v;
  }
  #pragma unroll
  for (int off = 32; off; off >>= 1){ s += __shfl_down(s, off); s2 += __shfl_down(s2, off); }
  s = __shfl(s, 0); s2 = __shfl(s2, 0);
  float m = s*(1.f/250.f);
  float r = rsqrtf(s2*(1.f/250.f) - m*m + 1e-5f);
  #pragma unroll
  for (int t = 0; t < 4; t++){
    int c = lane + t*64;
    if (c < 250) ctxs[jj][c] = fmaxf((vv[t]-m)*r, 0.f);
  }
  // att1: LN + tanh + dot(w2) + sigmoid (cols 256..355)
  float va[2];
  s = 0.f; s2 = 0.f;
  #pragma unroll
  for (int t = 0; t < 2; t++){
    int c = lane + t*64;
    float v = 0.f;
    if (c < 100)
      v = att1_b[c] + Pc[(size_t)row*384 + 256 + c] + Pc[MN + (size_t)row*384 + 256 + c];
    va[t] = v; s += v; s2 += v*v;
  }
  #pragma unroll
  for (int off = 32; off; off >>= 1){ s += __shfl_down(s, off); s2 += __shfl_down(s2, off); }
  s = __shfl(s, 0); s2 = __shfl(s2, 0);
  m = s*0.01f;
  r = rsqrtf(s2*0.01f - m*m + 1e-5f);
  float d = 0.f;
  #pragma unroll
  for (int t = 0; t < 2; t++){
    int c = lane + t*64;
    if (c < 100) d += tanhf((va[t]-m)*r)*w2[c];
  }
  #pragma unroll
  for (int off = 32; off; off >>= 1) d += __shfl_down(d, off);
  if (lane == 0) att_s[jj] = sigf(d + b2[0]);
  __syncthreads();
  for (int h = tid; h < 250; h += 448){
    float sum = 0.f;
    #pragma unroll
    for (int q = 0; q < 7; q++) sum += ctxs[q][h]*att_s[q];
    tot[(size_t)fi*1024 + 256 + h] = f2bf(sum);
  }
}

// ---------------- enc_conv1: x(n,64,64) -> FINAL bf16 elu(LN) (n,32,32,16) ----------------
__global__ __launch_bounds__(256) void enc_conv1_ig(
    const float* __restrict__ x, const float* __restrict__ w, const float* __restrict__ bias,
    short* __restrict__ outp)
{
  __shared__ __align__(16) float in_t[66*68];
  __shared__ short rawb[16384];
  __shared__ float sbuf[16];
  int n = blockIdx.x, tid = threadIdx.x;
  for (int l = tid; l < 66*68; l += 256) in_t[l] = 0.f;
  __syncthreads();
  const float* xin = x + (size_t)n*4096;
  for (int l4 = tid; l4 < 1024; l4 += 256){
    float4 v = *(const float4*)&xin[l4*4];
    int aa = (l4*4) >> 6, bb = (l4*4) & 63;
    float* dst = &in_t[(aa+1)*68 + bb + 1];
    dst[0]=v.x; dst[1]=v.y; dst[2]=v.z; dst[3]=v.w;
  }
  int o = tid & 15;
  float wr[16];
  #pragma unroll
  for (int t = 0; t < 16; t++) wr[t] = w[o*16 + t];
  float bv = bias[o];
  __syncthreads();
  float s = 0.f, s2 = 0.f;
  for (int r = 0; r < 64; r++){
    int idx = tid + (r<<8);
    int bq = (idx>>4)&31, aq = idx>>9;
    int a0 = 2*aq, b0 = 2*bq;
    float acc = bv;
    #pragma unroll
    for (int kw = 0; kw < 4; kw++){
      const float* row = &in_t[(a0+kw)*68 + b0];
      float2 p0 = *(const float2*)&row[0];
      float2 p1 = *(const float2*)&row[2];
      acc += p0.x*wr[0*4+kw] + p0.y*wr[1*4+kw] + p1.x*wr[2*4+kw] + p1.y*wr[3*4+kw];
    }
    rawb[idx] = f2bf(acc);
    s += acc; s2 += acc*acc;
  }
  block_reduce2(s, s2, sbuf);
  float m = s*(1.f/16384.f);
  float rs = rsqrtf(s2*(1.f/16384.f) - m*m + 1e-5f);
  short* op = outp + (size_t)n*16384;
  for (int l = tid; l < 16384; l += 256){
    float v = bf2f(rawb[l]);
    op[l] = f2bf(eluf((v-m)*rs));
  }
}

// ---------------- fused dec_conv1+2: padded LDS strides (72 / 40) to kill bank conflicts ----------------
__global__ __launch_bounds__(256) void dec_conv12_mfma(
    const short* __restrict__ in, const short* __restrict__ Bd1, const float* __restrict__ bias1,
    const short* __restrict__ Bd2, const float* __restrict__ bias2, short* __restrict__ outp)
{
  __shared__ __align__(16) short smem[18*18*40];   // conv1 staging (10*10*72=7200) then conv2 (18*18*40=12960)
  __shared__ float sbuf[16];
  int n = blockIdx.x, tid = threadIdx.x;
  for (int l = tid; l < 1800; l += 256) ((unsigned long long*)smem)[l] = 0ull;   // 7200 shorts
  __syncthreads();
  const short* ip = in + (size_t)n*4096;
  for (int l = tid; l < 1024; l += 256){
    int i4 = l & 15, sb = (l>>4)&7, sa = l>>7;
    *(uint2*)&smem[((sa+1)*10 + (sb+1))*72 + i4*4] = *(const uint2*)&ip[sa*512 + sb*64 + i4*4];
  }
  int wave = tid>>6, ln = tid&15, quad = (tid>>4)&3;
  int pa = wave & 1, pb = wave >> 1;
  bf16x8 bfr1[2][8];
  #pragma unroll
  for (int nt = 0; nt < 2; nt++){
    const short* Brow = Bd1 + (wave*32 + nt*16 + ln)*256;
    #pragma unroll
    for (int ks = 0; ks < 8; ks++)
      bfr1[nt][ks] = *(const bf16x8*)&Brow[ks*32 + quad*8];
  }
  __syncthreads();
  f32x4 z = {0.f,0.f,0.f,0.f};
  f32x4 acc[2][4] = {{z,z,z,z},{z,z,z,z}};
  #pragma unroll
  for (int ks = 0; ks < 8; ks++){
    int tap = ks>>1, ibase = (ks&1)*32 + quad*8;
    int da = tap & 1, db = tap >> 1;
    #pragma unroll
    for (int mt = 0; mt < 4; mt++){
      int p = mt*16 + ln;
      int ta = p>>3, tb = p&7;
      bf16x8 a = *(const bf16x8*)&smem[((ta+da+pa)*10 + (tb+db+pb))*72 + ibase];
      acc[0][mt] = __builtin_amdgcn_mfma_f32_16x16x32_bf16(a, bfr1[0][ks], acc[0][mt],0,0,0);
      acc[1][mt] = __builtin_amdgcn_mfma_f32_16x16x32_bf16(a, bfr1[1][ks], acc[1][mt],0,0,0);
    }
  }
  float s = 0.f, s2 = 0.f;
  #pragma unroll
  for (int nt = 0; nt < 2; nt++){
    float bz = bias1[nt*16 + ln];
    #pragma unroll
    for (int mt = 0; mt < 4; mt++)
      #pragma unroll
      for (int j = 0; j < 4; j++){
        float v = acc[nt][mt][j] + bz;
        acc[nt][mt][j] = v; s += v; s2 += v*v;
      }
  }
  block_reduce2(s, s2, sbuf);   // final barrier also guards smem reuse
  float m1 = s*(1.f/8192.f);
  float rs1 = rsqrtf(s2*(1.f/8192.f) - m1*m1 + 1e-5f);
  bf16x8 bfr2[4];
  {
    const short* Brow = Bd2 + (wave*16 + ln)*128;
    #pragma unroll
    for (int ks = 0; ks < 4; ks++)
      bfr2[ks] = *(const bf16x8*)&Brow[ks*32 + quad*8];
  }
  for (int l = tid; l < 3240; l += 256) ((unsigned long long*)smem)[l] = 0ull;   // 12960 shorts
  __syncthreads();
  #pragma unroll
  for (int nt = 0; nt < 2; nt++){
    int o = nt*16 + ln;
    #pragma unroll
    for (int mt = 0; mt < 4; mt++)
      #pragma unroll
      for (int j = 0; j < 4; j++){
        int p = mt*16 + quad*4 + j;
        int ta = p>>3, tb = p&7;
        int sa = 2*ta + pa, sb = 2*tb + pb;
        smem[((sa+1)*18 + (sb+1))*40 + o] = f2bf(fmaxf((acc[nt][mt][j]-m1)*rs1, 0.f));
      }
  }
  __syncthreads();
  f32x4 acc2[16] = {z,z,z,z,z,z,z,z,z,z,z,z,z,z,z,z};
  #pragma unroll
  for (int ks = 0; ks < 4; ks++){
    int da = ks & 1, db = ks >> 1;
    #pragma unroll
    for (int mt = 0; mt < 16; mt++){
      int p = mt*16 + ln;
      int ta = p>>4, tb = p&15;
      bf16x8 a = *(const bf16x8*)&smem[((ta+da+pa)*18 + (tb+db+pb))*40 + quad*8];
      acc2[mt] = __builtin_amdgcn_mfma_f32_16x16x32_bf16(a, bfr2[ks], acc2[mt],0,0,0);
    }
  }
  s = 0.f; s2 = 0.f;
  float bz2 = bias2[ln];
  #pragma unroll
  for (int mt = 0; mt < 16; mt++)
    #pragma unroll
    for (int j = 0; j < 4; j++){
      float v = acc2[mt][j] + bz2;
      acc2[mt][j] = v; s += v; s2 += v*v;
    }
  block_reduce2(s, s2, sbuf);
  float m = s*(1.f/16384.f);
  float rs = rsqrtf(s2*(1.f/16384.f) - m*m + 1e-5f);
  short* op = outp + (size_t)n*16384;
  #pragma unroll
  for (int mt = 0; mt < 16; mt++)
    #pragma unroll
    for (int j = 0; j < 4; j++){
      int p = mt*16 + quad*4 + j;
      int ta = p>>4, tb = p&15;
      op[(2*ta+pa)*512 + (2*tb+pb)*16 + ln] = f2bf(fmaxf((acc2[mt][j]-m)*rs, 0.f));
    }
}

// ---------------- dec_conv3 (final bf16 in) ----------------
__global__ __launch_bounds__(256) void dec_conv3_ig(
    const short* __restrict__ in, const float* __restrict__ CWT, const float* __restrict__ bias,
    float* __restrict__ outp)
{
  __shared__ __align__(16) float in_t[9792];   // [sa34][sb18][i16]
  __shared__ __align__(16) float wl[256];
  int bx = blockIdx.x;
  int n = bx >> 1, b0 = (bx & 1) * 32, tb0 = b0 >> 1;
  int tid = threadIdx.x;
  const short* ip = in + (size_t)n*16384;
  for (int l = tid; l < 9792; l += 256){
    int i = l & 15, sb = (l >> 4) % 18, sap = l / 288;
    int sa = sap - 1, sbg = tb0 - 1 + sb;
    float v = 0.f;
    if ((unsigned)sa < 32u && (unsigned)sbg < 32u)
      v = bf2f(ip[sa*512 + sbg*16 + i]);
    in_t[(sap*18 + sb)*16 + i] = v;
  }
  for (int l = tid; l < 256; l += 256) wl[l] = CWT[l];
  __syncthreads();
  float bv = bias[0];
  int bl = tid & 31, ath = tid >> 5;
  int b = b0 + bl;
  int tb = b >> 1, pb = b & 1;
  float* op = outp + (size_t)n*4096;
  #pragma unroll
  for (int j = 0; j < 8; j++){
    int a = ath*8 + j;
    int ta = a >> 1, pa = a & 1;
    float4 s4 = make_float4(0.f,0.f,0.f,0.f);
    #pragma unroll
    for (int db = 0; db < 2; db++){
      int sb = tb + db + (pb ? 0 : -1);
      int sbl = sb - (tb0 - 1);
      #pragma unroll
      for (int da = 0; da < 2; da++){
        int sa = ta + da + (pa ? 0 : -1);
        int sap = sa + 1;
        const float4* A4 = (const float4*)&in_t[(sap*18 + sbl)*16];
        const float4* B4 = (const float4*)&wl[((pb*2+pa)*4 + db*2+da)*16];
        #pragma unroll
        for (int q = 0; q < 4; q++){
          float4 av = A4[q], bw = B4[q];
          s4.x += av.x*bw.x; s4.y += av.y*bw.y;
          s4.z += av.z*bw.z; s4.w += av.w*bw.w;
        }
      }
    }
    op[a*64 + b] = sigf(bv + s4.x + s4.y + s4.z + s4.w);
  }
}

extern "C" void kernel_launch(void* const* d_in, const int* in_sizes, int n_in,
                              void* d_out, int out_size, void* d_ws, size_t ws_size,
                              hipStream_t stream) {
  const float* x      = (const float*)d_in[0];
  const float* state  = (const float*)d_in[1];
  const float* c1w    = (const float*)d_in[2];
  const float* c1b    = (const float*)d_in[3];
  const float* c2w    = (const float*)d_in[4];
  const float* c2b    = (const float*)d_in[5];
  const float* c3w    = (const float*)d_in[6];
  const float* c3b    = (const float*)d_in[7];
  const float* efc_w  = (const float*)d_in[8];
  const float* efc_b  = (const float*)d_in[9];
  const float* renc_w = (const float*)d_in[10];
  const float* renc_b = (const float*)d_in[11];
  const float* core_w = (const float*)d_in[12];
  const float* core_b = (const float*)d_in[13];
  const float* ctx_w  = (const float*)d_in[14];
  const float* ctx_b  = (const float*)d_in[15];
  const float* att1_w = (const float*)d_in[16];
  const float* att1_b = (const float*)d_in[17];
  const float* att2_w = (const float*)d_in[18];
  const float* att2_b = (const float*)d_in[19];
  const float* out_w  = (const float*)d_in[20];
  const float* out_b  = (const float*)d_in[21];
  const float* dfc1_w = (const float*)d_in[22];
  const float* dfc1_b = (const float*)d_in[23];
  const float* dfc2_w = (const float*)d_in[24];
  const float* dfc2_b = (const float*)d_in[25];
  const float* d1w    = (const float*)d_in[26];
  const float* d1b    = (const float*)d_in[27];
  const float* d2w    = (const float*)d_in[28];
  const float* d2b    = (const float*)d_in[29];
  const float* d3w    = (const float*)d_in[30];
  const float* d3b    = (const float*)d_in[31];

  float* wsf = (float*)d_ws;
  size_t o = 0;
  float* PB   = wsf + o; o += (size_t)2112*1024;    // split-K partials (fp32); fits 2x2688x384
  float* CWT3 = wsf + o; o += 256;
  // bf16 buffers (sizes in shorts; offsets in floats)
  short* E1b  = (short*)(wsf + o); o += (size_t)384*16384/2;   // enc1 final; later dec2 final
  short* E2b  = (short*)(wsf + o); o += (size_t)384*8192/2;    // conv2 raw bf16
  short* E3b  = (short*)(wsf + o); o += (size_t)384*4096/2;    // enc3 final; later G2 final
  short* TOTb = (short*)(wsf + o); o += (size_t)384*1024/2;    // [s1|pad|eff|pad|h]
  short* C1b  = (short*)(wsf + o); o += (size_t)2688*256/2;
  short* XRb  = (short*)(wsf + o); o += (size_t)384*256/2;
  short* G1b  = (short*)(wsf + o); o += (size_t)384*512/2;
  short* SBF  = (short*)(wsf + o); o += (size_t)384*256/2;
  short* BtC2 = (short*)(wsf + o); o += 8192/2;
  short* BtC3 = (short*)(wsf + o); o += 32768/2;
  short* BD1  = (short*)(wsf + o); o += 32768/2;
  short* BD2  = (short*)(wsf + o); o += 8192/2;
  short* BT_efc    = (short*)(wsf + o); o += 2097152/2;
  short* BT_renc   = (short*)(wsf + o); o += 64000/2;
  short* BT_core   = (short*)(wsf + o); o += 128000/2;
  short* BT_ctxatt = (short*)(wsf + o); o += 98304/2;   // [384 rows][256]: 0..249 ctx, 256..355 att1
  short* BT_out    = (short*)(wsf + o); o += 256000/2;
  short* BT_dfc1   = (short*)(wsf + o); o += 131072/2;
  short* BT_dfc2   = (short*)(wsf + o); o += 2097152/2;
  short* D2b = E1b;
  short* G2b = E3b;

  float* xout = (float*)d_out;
  float* sout = xout + (size_t)384*4096;

  // one prep kernel: weight transposes + folds + state cvt + pad zeroing
  prep_combined<<<1448, 256, 0, stream>>>(
      efc_w, BT_efc, dfc2_w, BT_dfc2, out_w, BT_out, core_w, BT_core,
      dfc1_w, BT_dfc1, renc_w, BT_renc, ctx_w, att1_w, BT_ctxatt,
      d3w, CWT3, c2w, BtC2, c3w, BtC3, d1w, BD1, d2w, BD2, state, SBF, TOTb);

  // encoder: conv1, conv2 gather-GEMM, fused LN2+conv3+LN3
  enc_conv1_ig<<<384, 256, 0, stream>>>(x, c1w, c1b, E1b);
  gemm_conv2g<<<768, 256, 0, stream>>>(E1b, BtC2, E2b);
  enc_conv3_full<<<384, 256, 0, stream>>>(E2b, c2b, BtC3, c3b, E3b);
  gemm_mfma<<<dim3(8,6,8), 256, 0, stream>>>(E3b, BT_efc, PB, 384, 512, 4096, 512);
  reduce_ln<<<384, 256, 0, stream>>>(PB, efc_b, TOTb+512, 384, 512, 8, 1024, 2, 1, -1);

  // state path
  gemm_mfma<<<dim3(4,6,8), 256, 0, stream>>>(SBF, BT_renc, PB, 384, 250, 256, 32);
  reduce_ln<<<384, 256, 0, stream>>>(PB, renc_b, TOTb, 384, 250, 8, 1024, 1, 1, -1);
  gemm_core_mfma<<<dim3(4,42,2), 256, 0, stream>>>(TOTb, BT_core, PB, 2688, 250, 256);
  reduce_ln<<<2688, 256, 0, stream>>>(PB, core_b, C1b, 2688, 250, 2, 256, 1, 1, -1);
  gemm_mfma<<<dim3(6,42,2), 256, 0, stream>>>(C1b, BT_ctxatt, PB, 2688, 384, 256, 128);
  ctx_att_effect<<<384, 448, 0, stream>>>(PB, ctx_b, att1_b, att2_w, att2_b, TOTb);

  // combine
  gemm_mfma<<<dim3(4,6,8), 256, 0, stream>>>(TOTb, BT_out, PB, 384, 250, 1024, 128);
  reduce_ns<<<384, 256, 0, stream>>>(PB, out_b, XRb, sout, 384, 250, 8);

  // decoder FC
  gemm_mfma<<<dim3(8,6,4), 256, 0, stream>>>(XRb, BT_dfc1, PB, 384, 512, 256, 64);
  reduce_ln<<<384, 256, 0, stream>>>(PB, dfc1_b, G1b, 384, 512, 4, 512, 1, 1, -1);
  gemm_mfma<<<dim3(64,6,1), 256, 0, stream>>>(G1b, BT_dfc2, PB, 384, 4096, 512, 512);
  reduce_ln<<<384, 256, 0, stream>>>(PB, dfc2_b, G2b, 384, 4096, 1, 4096, 1, 1, -1);

  // decoder convs (fused conv1+2 with padded LDS, then conv3)
  dec_conv12_mfma<<<384, 256, 0, stream>>>(G2b, BD1, d1b, BD2, d2b, D2b);
  dec_conv3_ig<<<768, 256, 0, stream>>>(D2b, CWT3, d3b, xout);

  (void)in_sizes; (void)n_in; (void)out_size; (void)ws_size;
}

// Round 10
// 293.741 us; speedup vs baseline: 1.1565x; 1.0974x over previous
//
#include <hip/hip_runtime.h>
#include <hip/hip_bf16.h>
#include <math.h>

typedef __attribute__((ext_vector_type(8))) short bf16x8;
typedef __attribute__((ext_vector_type(4))) float f32x4;

__device__ __forceinline__ float eluf(float v){ return v > 0.f ? v : expm1f(v); }
__device__ __forceinline__ float sigf(float v){ return 1.f/(1.f+expf(-v)); }
__device__ __forceinline__ unsigned short f2bf(float f){
  unsigned u = __float_as_uint(f);
  u += 0x7FFFu + ((u >> 16) & 1u);          // round-to-nearest-even
  return (unsigned short)(u >> 16);
}
__device__ __forceinline__ float bf2f(short s){
  return __uint_as_float(((unsigned)(unsigned short)s) << 16);
}

// ---------------- block-wide sum & sumsq reduction ----------------
__device__ __forceinline__ void block_reduce2(float& a, float& b, float* sbuf){
  __syncthreads();
  for (int off = 32; off; off >>= 1){
    a += __shfl_down(a, off);
    b += __shfl_down(b, off);
  }
  int lane = threadIdx.x & 63, w = threadIdx.x >> 6;
  if (lane == 0){ sbuf[2*w] = a; sbuf[2*w+1] = b; }
  __syncthreads();
  if (threadIdx.x == 0){
    int nw = blockDim.x >> 6;
    float sa = 0.f, sb = 0.f;
    for (int i = 0; i < nw; i++){ sa += sbuf[2*i]; sb += sbuf[2*i+1]; }
    sbuf[0] = sa; sbuf[1] = sb;
  }
  __syncthreads();
  a = sbuf[0]; b = sbuf[1];
}

// ---------------- prep helpers ----------------
__device__ __forceinline__ float fold_sum(const float* __restrict__ w, int O, int I,
                                          int o, int i, int pa, int pb, int da, int db){
  float s = 0.f;
  for (int kh = 0; kh < 4; kh++){
    bool inh = (pb==0) ? (db==0 ? (kh==0) : (kh>=1)) : (db==0 ? (kh<=2) : (kh==3));
    if (!inh) continue;
    for (int kw = 0; kw < 4; kw++){
      bool inw = (pa==0) ? (da==0 ? (kw==0) : (kw>=1)) : (da==0 ? (kw<=2) : (kw==3));
      if (!inw) continue;
      s += w[((o*I + i)*4 + kh)*4 + kw];
    }
  }
  return s;
}
__device__ __forceinline__ void fold_elem(const float* __restrict__ w, float* __restrict__ CW,
                                          int O, int I, int l){
  int o = l % O; int q = l / O;
  int da = q & 1, db = (q>>1)&1, pa = (q>>2)&1, pb = (q>>3)&1, i = q>>4;
  CW[(((pb*2+pa)*4 + db*2+da)*I + i)*O + o] = fold_sum(w, O, I, o, i, pa, pb, da, db);
}
__device__ __forceinline__ void cvtc2_elem(const float* __restrict__ w, short* __restrict__ D, int l){
  int i = l & 15, t = (l>>4) & 15, o = l>>8;        // k = t*16 + i
  D[l] = (short)f2bf(w[(o*16 + i)*16 + t]);
}
__device__ __forceinline__ void cvtc3_elem(const float* __restrict__ w, short* __restrict__ D, int l){
  int i = l & 31, t = (l>>5) & 15, o = l>>9;        // k = t*32 + i
  D[l] = (short)f2bf(w[(o*32 + i)*16 + t]);
}
__device__ __forceinline__ void foldd1_elem(const float* __restrict__ w, short* __restrict__ D, int l){
  int i = l & 63, tap = (l>>6)&3, o = (l>>8)&31, ph = l>>13;
  D[l] = (short)f2bf(fold_sum(w, 32, 64, o, i, ph&1, ph>>1, tap&1, tap>>1));
}
__device__ __forceinline__ void foldd2_elem(const float* __restrict__ w, short* __restrict__ D, int l){
  int i = l & 31, tap = (l>>5)&3, o = (l>>7)&15, ph = l>>11;
  D[l] = (short)f2bf(fold_sum(w, 16, 32, o, i, ph&1, ph>>1, tap&1, tap>>1));
}

// ---------------- combined prep: weight transposes (blocks 0..1191) + small packs ----------------
__global__ __launch_bounds__(256) void prep_combined(
  const float* __restrict__ efc,  short* __restrict__ Defc,
  const float* __restrict__ dfc2, short* __restrict__ Ddfc2,
  const float* __restrict__ outw, short* __restrict__ Dout,
  const float* __restrict__ corew,short* __restrict__ Dcore,
  const float* __restrict__ dfc1, short* __restrict__ Ddfc1,
  const float* __restrict__ renc, short* __restrict__ Drenc,
  const float* __restrict__ ctx,  const float* __restrict__ att1,
  short* __restrict__ Dctxatt,
  const float* __restrict__ d3w, float* __restrict__ CWT3,
  const float* __restrict__ c2w, short* __restrict__ BtC2,
  const float* __restrict__ c3w, short* __restrict__ BtC3,
  const float* __restrict__ d1w, short* __restrict__ BD1,
  const float* __restrict__ d2w, short* __restrict__ BD2,
  const float* __restrict__ state, short* __restrict__ SBF,
  short* __restrict__ TOTb)
{
  int bx = blockIdx.x;
  if (bx >= 1192){
    const int F3=256, P2=F3+8192, P3=P2+32768, P4=P3+32768, P5=P4+8192,
              ST=P5+98304, TP=ST+4608, TOTAL=TP+8704;
    for (int l = (bx-1192)*256 + threadIdx.x; l < TOTAL; l += 256*256){
      if (l < F3)      fold_elem(d3w, CWT3, 1, 16, l);
      else if (l < P2) cvtc2_elem(c2w, BtC2, l - F3);
      else if (l < P3) cvtc3_elem(c3w, BtC3, l - P2);
      else if (l < P4) foldd1_elem(d1w, BD1, l - P3);
      else if (l < P5) foldd2_elem(d2w, BD2, l - P4);
      else if (l < ST){
        int q = l - P5;             // state -> bf16 [384][256], zero pad
        int n = q >> 8, k = q & 255;
        SBF[q] = (k < 250) ? (short)f2bf(state[n*250 + k]) : (short)0;
      } else if (l < TP){
        int q = l - ST;             // zero TOT pad cols: 250..255, 506..511
        int row = q / 12, cc = q % 12;
        int col = cc < 6 ? 250 + cc : 506 + (cc - 6);
        TOTb[row*1024 + col] = 0;
      } else {
        int q = l - TP;             // zero ctxatt pad rows: 250..255, 356..383
        int r = q >> 8, cc = q & 255;
        int row = r < 6 ? 250 + r : 356 + (r - 6);
        Dctxatt[row*256 + cc] = 0;
      }
    }
    return;
  }
  const float* W; short* D; int K, N, Kp, base, mode = 0;
  if      (bx < 512) { W=efc;  D=Defc;  K=4096; N=512;  Kp=4096; base=0;    }
  else if (bx < 1024){ W=dfc2; D=Ddfc2; K=512;  N=4096; Kp=512;  base=512;  }
  else if (bx < 1088){ W=outw; D=Dout;  K=1012; N=250;  Kp=1024; base=1024; mode=2; }
  else if (bx < 1120){ W=corew;D=Dcore; K=500;  N=250;  Kp=512;  base=1088; mode=1; }
  else if (bx < 1152){ W=dfc1; D=Ddfc1; K=250;  N=512;  Kp=256;  base=1120; }
  else if (bx < 1168){ W=renc; D=Drenc; K=250;  N=250;  Kp=256;  base=1152; }
  else if (bx < 1184){ W=ctx;  D=Dctxatt;         K=250; N=250; Kp=256; base=1168; }
  else               { W=att1; D=Dctxatt + 65536; K=250; N=100; Kp=256; base=1184; }
  int t = bx - base;
  int tpr = Kp >> 6;
  int tk = t % tpr, tn = t / tpr;
  __shared__ short tile[64][65];
  int c = threadIdx.x & 63, r4 = threadIdx.x >> 6;
  int n0 = tn*64, k0 = tk*64;
  #pragma unroll 4
  for (int p = 0; p < 16; p++){
    int r = r4*16 + p;
    int k = k0 + r, n = n0 + c;
    int ksrc = k; bool valid;
    if (mode == 0) valid = (k < K);
    else if (mode == 1){ valid = (k < 250) || (k >= 256 && k < 506); ksrc = k < 256 ? k : k - 6; }
    else { valid = (k < 250) || (k >= 256 && k < 506) || (k >= 512);
           ksrc = k < 256 ? k : (k < 512 ? k - 6 : k - 12); }
    float v = (valid && n < N) ? W[(size_t)ksrc*N + n] : 0.f;
    tile[c][r] = (short)f2bf(v);
  }
  __syncthreads();
  #pragma unroll 4
  for (int p = 0; p < 16; p++){
    int nn = r4*16 + p;
    int n = n0 + nn;
    if (n < N) D[(size_t)n*Kp + k0 + c] = tile[nn][c];
  }
}

// ---------------- MFMA bf16 split-K GEMM body ----------------
__device__ __forceinline__ void gemm_body(
    const short* __restrict__ Ab, const short* __restrict__ Bt,
    float* __restrict__ P, int M, int N, int Kp, int Kc,
    int bxx, int byy, int bzz)
{
  __shared__ __align__(16) short As[64*32];
  __shared__ __align__(16) short Bs[64*32];
  int tid = threadIdx.x;
  int bm = byy*64, bn = bxx*64;
  int kb = bzz * Kc;
  int kend = kb + Kc;

  int r = tid >> 2, c = tid & 3;
  const short* Arow = Ab + (size_t)(bm + r)*Kp;
  int gn = bn + r;
  bool bval = gn < N;
  const short* Brow = Bt + (size_t)gn*Kp;

  uint4 hA, hB;
  auto load_regs = [&](int k0){
    hA = *(const uint4*)&Arow[k0 + c*8];
    hB = bval ? *(const uint4*)&Brow[k0 + c*8] : make_uint4(0,0,0,0);
  };
  auto write_lds = [&](){
    *(uint4*)&As[r*32 + c*8] = hA;
    *(uint4*)&Bs[r*32 + c*8] = hB;
  };

  int wave = tid >> 6;
  int ln = tid & 15, quad = (tid >> 4) & 3;
  int wr = (wave >> 1) * 32, wc = (wave & 1) * 32;

  f32x4 zero = {0.f, 0.f, 0.f, 0.f};
  f32x4 acc[2][2] = {{zero, zero}, {zero, zero}};

  load_regs(kb);
  write_lds();
  __syncthreads();
  for (int k0 = kb; k0 < kend; k0 += 32){
    int nxt = k0 + 32;
    if (nxt < kend) load_regs(nxt);
    bf16x8 a0 = *(const bf16x8*)&As[(wr +      ln)*32 + quad*8];
    bf16x8 a1 = *(const bf16x8*)&As[(wr + 16 + ln)*32 + quad*8];
    bf16x8 b0 = *(const bf16x8*)&Bs[(wc +      ln)*32 + quad*8];
    bf16x8 b1 = *(const bf16x8*)&Bs[(wc + 16 + ln)*32 + quad*8];
    acc[0][0] = __builtin_amdgcn_mfma_f32_16x16x32_bf16(a0, b0, acc[0][0], 0, 0, 0);
    acc[0][1] = __builtin_amdgcn_mfma_f32_16x16x32_bf16(a0, b1, acc[0][1], 0, 0, 0);
    acc[1][0] = __builtin_amdgcn_mfma_f32_16x16x32_bf16(a1, b0, acc[1][0], 0, 0, 0);
    acc[1][1] = __builtin_amdgcn_mfma_f32_16x16x32_bf16(a1, b1, acc[1][1], 0, 0, 0);
    __syncthreads();
    if (nxt < kend){ write_lds(); __syncthreads(); }
  }

  float* Pout = P + (size_t)bzz*M*N;
  #pragma unroll
  for (int t = 0; t < 2; t++)
    #pragma unroll
    for (int u = 0; u < 2; u++)
      #pragma unroll
      for (int j = 0; j < 4; j++){
        int row = bm + wr + t*16 + quad*4 + j;
        int col = bn + wc + u*16 + ln;
        if (col < N) Pout[(size_t)row*N + col] = acc[t][u][j];
      }
}

__global__ __launch_bounds__(256) void gemm_mfma(
    const short* __restrict__ Ab, const short* __restrict__ Bt,
    float* __restrict__ P, int M, int N, int Kp, int Kc)
{
  gemm_body(Ab, Bt, P, M, N, Kp, Kc, blockIdx.x, blockIdx.y, blockIdx.z);
}

// ---------------- conv2 gather-GEMM body ----------------
__device__ __forceinline__ void conv2g_body(
    const short* __restrict__ In, const short* __restrict__ Bt,
    short* __restrict__ Out, int bxx)
{
  __shared__ __align__(16) short As[128*32];
  __shared__ __align__(16) short Bs[32*32];
  int tid = threadIdx.x;
  int bm = bxx*128;

  int ra = tid >> 1, ca = (tid & 1)*16;
  int gr = bm + ra;
  int n = gr >> 8, pos = gr & 255;
  int oa = pos >> 4, ob = pos & 15;
  const short* ibase = In + (size_t)n*16384;
  int rb = tid >> 2, cb = (tid & 3)*8;
  const short* Brow = Bt + rb*256;
  bool bact = tid < 128;

  uint4 hA0, hA1, hB;
  auto load_regs = [&](int k0){
    #pragma unroll
    for (int h = 0; h < 2; h++){
      int k = k0 + ca + h*8;
      int tap = k >> 4;
      int ai = 2*oa + (tap & 3) - 1, bi = 2*ob + (tap >> 2) - 1;
      bool v = ((unsigned)ai < 32u) && ((unsigned)bi < 32u);
      uint4 tv = v ? *(const uint4*)&ibase[ai*512 + bi*16 + (k & 15)] : make_uint4(0,0,0,0);
      if (h == 0) hA0 = tv; else hA1 = tv;
    }
    if (bact) hB = *(const uint4*)&Brow[k0 + cb];
  };
  auto write_lds = [&](){
    *(uint4*)&As[ra*32 + ca] = hA0;
    *(uint4*)&As[ra*32 + ca + 8] = hA1;
    if (bact) *(uint4*)&Bs[rb*32 + cb] = hB;
  };

  int wave = tid >> 6, ln = tid & 15, quad = (tid >> 4) & 3;
  int wr = wave * 32;

  f32x4 zero = {0.f,0.f,0.f,0.f};
  f32x4 acc[2][2] = {{zero,zero},{zero,zero}};
  load_regs(0); write_lds(); __syncthreads();
  for (int k0 = 0; k0 < 256; k0 += 32){
    int nxt = k0 + 32;
    if (nxt < 256) load_regs(nxt);
    bf16x8 a0 = *(const bf16x8*)&As[(wr +      ln)*32 + quad*8];
    bf16x8 a1 = *(const bf16x8*)&As[(wr + 16 + ln)*32 + quad*8];
    bf16x8 b0 = *(const bf16x8*)&Bs[(     ln)*32 + quad*8];
    bf16x8 b1 = *(const bf16x8*)&Bs[(16 + ln)*32 + quad*8];
    acc[0][0] = __builtin_amdgcn_mfma_f32_16x16x32_bf16(a0, b0, acc[0][0], 0, 0, 0);
    acc[0][1] = __builtin_amdgcn_mfma_f32_16x16x32_bf16(a0, b1, acc[0][1], 0, 0, 0);
    acc[1][0] = __builtin_amdgcn_mfma_f32_16x16x32_bf16(a1, b0, acc[1][0], 0, 0, 0);
    acc[1][1] = __builtin_amdgcn_mfma_f32_16x16x32_bf16(a1, b1, acc[1][1], 0, 0, 0);
    __syncthreads();
    if (nxt < 256){ write_lds(); __syncthreads(); }
  }
  #pragma unroll
  for (int t = 0; t < 2; t++)
    #pragma unroll
    for (int u = 0; u < 2; u++)
      #pragma unroll
      for (int j = 0; j < 4; j++){
        int row = bm + wr + t*16 + quad*4 + j;
        int col = u*16 + ln;
        Out[(size_t)row*32 + col] = (short)f2bf(acc[t][u][j]);
      }
}

// ---------------- fused enc conv3 body: LN2+ELU + conv3 MFMA + LN3+ELU ----------------
__device__ __forceinline__ void conv3_full_body(
    const short* __restrict__ E2raw, const float* __restrict__ bias2,
    const short* __restrict__ Bt3, const float* __restrict__ bias3,
    short* __restrict__ outp, int n)
{
  __shared__ __align__(16) short lsamp[18*18*40];
  __shared__ float sbuf[16];
  int tid = threadIdx.x;
  const short* ip = E2raw + (size_t)n*8192;
  float vv[32];
  float s = 0.f, s2 = 0.f;
  #pragma unroll
  for (int t = 0; t < 4; t++){
    bf16x8 v8 = *(const bf16x8*)&ip[(t*256 + tid)*8];
    #pragma unroll
    for (int j = 0; j < 8; j++){
      int e = (t*256 + tid)*8 + j;
      float v = bf2f(v8[j]) + bias2[e & 31];
      vv[t*8+j] = v; s += v; s2 += v*v;
    }
  }
  block_reduce2(s, s2, sbuf);
  float m2 = s*(1.f/8192.f);
  float rs2 = rsqrtf(s2*(1.f/8192.f) - m2*m2 + 1e-5f);
  for (int l = tid; l < 18*18*40/4; l += 256) ((unsigned long long*)lsamp)[l] = 0ull;
  __syncthreads();
  #pragma unroll
  for (int t = 0; t < 4; t++){
    int e0 = (t*256 + tid)*8;
    int slot = e0 >> 5, ch0 = e0 & 31;
    int a = slot >> 4, b = slot & 15;
    bf16x8 o8;
    #pragma unroll
    for (int j = 0; j < 8; j++)
      o8[j] = (short)f2bf(eluf((vv[t*8+j]-m2)*rs2));
    *(bf16x8*)&lsamp[((a+1)*18 + (b+1))*40 + ch0] = o8;
  }
  int wave = tid>>6, ln = tid&15, quad = (tid>>4)&3;
  int o3 = wave*16 + ln;
  bf16x8 bfr3[16];
  {
    const short* Brow = Bt3 + o3*512;
    #pragma unroll
    for (int ks = 0; ks < 16; ks++)
      bfr3[ks] = *(const bf16x8*)&Brow[ks*32 + quad*8];
  }
  __syncthreads();
  f32x4 z = {0.f,0.f,0.f,0.f};
  f32x4 acc3[4] = {z,z,z,z};
  #pragma unroll
  for (int ks = 0; ks < 16; ks++){
    int kh = ks>>2, kw = ks&3;
    #pragma unroll
    for (int mt = 0; mt < 4; mt++){
      int p = mt*16 + ln;
      int oa = p>>3, ob = p&7;
      bf16x8 a = *(const bf16x8*)&lsamp[((2*oa+kw)*18 + (2*ob+kh))*40 + quad*8];
      acc3[mt] = __builtin_amdgcn_mfma_f32_16x16x32_bf16(a, bfr3[ks], acc3[mt],0,0,0);
    }
  }
  s = 0.f; s2 = 0.f;
  float bz3 = bias3[o3];
  #pragma unroll
  for (int mt = 0; mt < 4; mt++)
    #pragma unroll
    for (int j = 0; j < 4; j++){
      float v = acc3[mt][j] + bz3;
      acc3[mt][j] = v; s += v; s2 += v*v;
    }
  block_reduce2(s, s2, sbuf);
  float m3 = s*(1.f/4096.f);
  float rs3 = rsqrtf(s2*(1.f/4096.f) - m3*m3 + 1e-5f);
  short* op = outp + (size_t)n*4096;
  #pragma unroll
  for (int mt = 0; mt < 4; mt++)
    #pragma unroll
    for (int j = 0; j < 4; j++){
      int p = mt*16 + quad*4 + j;
      int oa = p>>3, ob = p&7;
      op[oa*512 + ob*64 + o3] = f2bf(eluf((acc3[mt][j]-m3)*rs3));
    }
}

// ---------------- core GEMM body (A gathered from padded TOT) ----------------
__device__ __forceinline__ void gemm_core_body(
    const short* __restrict__ Tb, const short* __restrict__ Bt,
    float* __restrict__ P, int M, int N, int Kc,
    int bxx, int byy, int bzz)
{
  __shared__ __align__(16) short As[64*32];
  __shared__ __align__(16) short Bs[64*32];
  int tid = threadIdx.x;
  int bm = byy*64, bn = bxx*64;
  int kb = bzz * Kc;
  int kend = kb + Kc;

  int r = tid >> 2, c = tid & 3;
  int gr = bm + r;
  int jj2 = gr % 7, fi2 = gr / 7;
  int ii = fi2 & 7, j2 = fi2 >> 3;
  int jidx = jj2 < ii ? jj2 : jj2 + 1;
  const short* own = Tb + (size_t)fi2*1024;
  const short* oth = Tb + (size_t)(j2*8 + jidx)*1024;
  int gn = bn + r;
  bool bval = gn < N;
  const short* Brow = Bt + (size_t)gn*512;

  uint4 hA, hB;
  auto load_regs = [&](int k0){
    int kk = k0 + c*8;
    const short* src = (kk & 256) ? oth : own;
    hA = *(const uint4*)&src[kk & 255];
    hB = bval ? *(const uint4*)&Brow[kk] : make_uint4(0,0,0,0);
  };
  auto write_lds = [&](){
    *(uint4*)&As[r*32 + c*8] = hA;
    *(uint4*)&Bs[r*32 + c*8] = hB;
  };

  int wave = tid >> 6;
  int ln = tid & 15, quad = (tid >> 4) & 3;
  int wr = (wave >> 1) * 32, wc = (wave & 1) * 32;

  f32x4 zero = {0.f, 0.f, 0.f, 0.f};
  f32x4 acc[2][2] = {{zero, zero}, {zero, zero}};

  load_regs(kb);
  write_lds();
  __syncthreads();
  for (int k0 = kb; k0 < kend; k0 += 32){
    int nxt = k0 + 32;
    if (nxt < kend) load_regs(nxt);
    bf16x8 a0 = *(const bf16x8*)&As[(wr +      ln)*32 + quad*8];
    bf16x8 a1 = *(const bf16x8*)&As[(wr + 16 + ln)*32 + quad*8];
    bf16x8 b0 = *(const bf16x8*)&Bs[(wc +      ln)*32 + quad*8];
    bf16x8 b1 = *(const bf16x8*)&Bs[(wc + 16 + ln)*32 + quad*8];
    acc[0][0] = __builtin_amdgcn_mfma_f32_16x16x32_bf16(a0, b0, acc[0][0], 0, 0, 0);
    acc[0][1] = __builtin_amdgcn_mfma_f32_16x16x32_bf16(a0, b1, acc[0][1], 0, 0, 0);
    acc[1][0] = __builtin_amdgcn_mfma_f32_16x16x32_bf16(a1, b0, acc[1][0], 0, 0, 0);
    acc[1][1] = __builtin_amdgcn_mfma_f32_16x16x32_bf16(a1, b1, acc[1][1], 0, 0, 0);
    __syncthreads();
    if (nxt < kend){ write_lds(); __syncthreads(); }
  }

  float* Pout = P + (size_t)bzz*M*N;
  #pragma unroll
  for (int t = 0; t < 2; t++)
    #pragma unroll
    for (int u = 0; u < 2; u++)
      #pragma unroll
      for (int j = 0; j < 4; j++){
        int row = bm + wr + t*16 + quad*4 + j;
        int col = bn + wc + u*16 + ln;
        if (col < N) Pout[(size_t)row*N + col] = acc[t][u][j];
      }
}

// ---------------- reduce_ln body ----------------
__device__ __forceinline__ void reduce_ln_body(
    const float* __restrict__ Pp, const float* __restrict__ bias,
    void* __restrict__ outp, int M, int N, int KS, int os, int act, int obf, int bmask,
    int row)
{
  __shared__ float rowbuf[4096];
  __shared__ float sbuf[16];
  size_t MN = (size_t)M*N;
  float s = 0.f, s2 = 0.f;
  for (int c = threadIdx.x; c < N; c += 256){
    float v = bias[c & bmask];
    for (int ks = 0; ks < KS; ks++) v += Pp[ks*MN + (size_t)row*N + c];
    rowbuf[c] = v; s += v; s2 += v*v;
  }
  block_reduce2(s, s2, sbuf);
  float m = s / N;
  float r = rsqrtf(s2/N - m*m + 1e-5f);
  for (int c = threadIdx.x; c < N; c += 256){
    float v = (rowbuf[c]-m)*r;
    if (act == 1) v = fmaxf(v, 0.f);
    else if (act == 2) v = eluf(v);
    else if (act == 3) v = tanhf(v);
    if (obf) ((short*)outp)[(size_t)row*os + c] = f2bf(v);
    else     ((float*)outp)[(size_t)row*os + c] = v;
  }
}

__global__ __launch_bounds__(256) void reduce_ln(
    const float* __restrict__ Pp, const float* __restrict__ bias,
    void* __restrict__ outp, int M, int N, int KS, int os, int act, int obf, int bmask)
{
  reduce_ln_body(Pp, bias, outp, M, N, KS, os, act, obf, bmask, blockIdx.x);
}

// ---------------- enc_conv1 body ----------------
__device__ __forceinline__ void enc_conv1_body(
    const float* __restrict__ x, const float* __restrict__ w, const float* __restrict__ bias,
    short* __restrict__ outp, int n)
{
  __shared__ __align__(16) float in_t[66*68];
  __shared__ short rawb[16384];
  __shared__ float sbuf[16];
  int tid = threadIdx.x;
  for (int l = tid; l < 66*68; l += 256) in_t[l] = 0.f;
  __syncthreads();
  const float* xin = x + (size_t)n*4096;
  for (int l4 = tid; l4 < 1024; l4 += 256){
    float4 v = *(const float4*)&xin[l4*4];
    int aa = (l4*4) >> 6, bb = (l4*4) & 63;
    float* dst = &in_t[(aa+1)*68 + bb + 1];
    dst[0]=v.x; dst[1]=v.y; dst[2]=v.z; dst[3]=v.w;
  }
  int o = tid & 15;
  float wr[16];
  #pragma unroll
  for (int t = 0; t < 16; t++) wr[t] = w[o*16 + t];
  float bv = bias[o];
  __syncthreads();
  float s = 0.f, s2 = 0.f;
  for (int r = 0; r < 64; r++){
    int idx = tid + (r<<8);
    int bq = (idx>>4)&31, aq = idx>>9;
    int a0 = 2*aq, b0 = 2*bq;
    float acc = bv;
    #pragma unroll
    for (int kw = 0; kw < 4; kw++){
      const float* row = &in_t[(a0+kw)*68 + b0];
      float2 p0 = *(const float2*)&row[0];
      float2 p1 = *(const float2*)&row[2];
      acc += p0.x*wr[0*4+kw] + p0.y*wr[1*4+kw] + p1.x*wr[2*4+kw] + p1.y*wr[3*4+kw];
    }
    rawb[idx] = f2bf(acc);
    s += acc; s2 += acc*acc;
  }
  block_reduce2(s, s2, sbuf);
  float m = s*(1.f/16384.f);
  float rs = rsqrtf(s2*(1.f/16384.f) - m*m + 1e-5f);
  short* op = outp + (size_t)n*16384;
  for (int l = tid; l < 16384; l += 256){
    float v = bf2f(rawb[l]);
    op[l] = f2bf(eluf((v-m)*rs));
  }
}

// ---------------- fused parallel-path launches ----------------
// F_a: enc_conv1 [0,384) || renc GEMM [384,576)
__global__ __launch_bounds__(256) void fuse_a(
    const float* __restrict__ x, const float* __restrict__ c1w, const float* __restrict__ c1b,
    short* __restrict__ E1b,
    const short* __restrict__ SBF, const short* __restrict__ BT_renc, float* __restrict__ PB_renc)
{
  int b = blockIdx.x;
  if (b < 384){
    enc_conv1_body(x, c1w, c1b, E1b, b);
  } else {
    int id = b - 384;                       // dim3(4,6,8)
    gemm_body(SBF, BT_renc, PB_renc, 384, 250, 256, 32, id & 3, (id >> 2) % 6, id / 24);
  }
}

// F_b: renc LN [0,384) || conv2 GEMM [384,1152)
__global__ __launch_bounds__(256) void fuse_b(
    const float* __restrict__ PB_renc, const float* __restrict__ renc_b, short* __restrict__ TOTb,
    const short* __restrict__ E1b, const short* __restrict__ BtC2, short* __restrict__ E2b)
{
  int b = blockIdx.x;
  if (b < 384){
    reduce_ln_body(PB_renc, renc_b, TOTb, 384, 250, 8, 1024, 1, 1, -1, b);
  } else {
    conv2g_body(E1b, BtC2, E2b, b - 384);
  }
}

// F_c: core GEMM [0,336) || conv3_full [336,720)
__global__ __launch_bounds__(256) void fuse_c(
    const short* __restrict__ TOTb, const short* __restrict__ BT_core, float* __restrict__ PB_core,
    const short* __restrict__ E2b, const float* __restrict__ c2b,
    const short* __restrict__ BtC3, const float* __restrict__ c3b, short* __restrict__ E3b)
{
  int b = blockIdx.x;
  if (b < 336){                             // dim3(4,42,2)
    gemm_core_body(TOTb, BT_core, PB_core, 2688, 250, 256, b % 4, (b / 4) % 42, b / 168);
  } else {
    conv3_full_body(E2b, c2b, BtC3, c3b, E3b, b - 336);
  }
}

// F_d: core LN [0,2688) || efc GEMM [2688,3072)
__global__ __launch_bounds__(256) void fuse_d(
    const float* __restrict__ PB_core, const float* __restrict__ core_b, short* __restrict__ C1b,
    const short* __restrict__ E3b, const short* __restrict__ BT_efc, float* __restrict__ PB_efc)
{
  int b = blockIdx.x;
  if (b < 2688){
    reduce_ln_body(PB_core, core_b, C1b, 2688, 250, 2, 256, 1, 1, -1, b);
  } else {
    int id = b - 2688;                      // dim3(8,6,8)
    gemm_body(E3b, BT_efc, PB_efc, 384, 512, 4096, 512, id & 7, (id >> 3) % 6, id / 48);
  }
}

// F_e: ctxatt GEMM [0,504) || efc LN [504,888)
__global__ __launch_bounds__(256) void fuse_e(
    const short* __restrict__ C1b, const short* __restrict__ BT_ctxatt, float* __restrict__ PB_ctxatt,
    const float* __restrict__ PB_efc, const float* __restrict__ efc_b, short* __restrict__ TOTh)
{
  int b = blockIdx.x;
  if (b < 504){                             // dim3(6,42,2)
    gemm_body(C1b, BT_ctxatt, PB_ctxatt, 2688, 384, 256, 128, b % 6, (b / 6) % 42, b / 252);
  } else {
    reduce_ln_body(PB_efc, efc_b, TOTh, 384, 512, 8, 1024, 2, 1, -1, b - 504);
  }
}

// ---------------- fused NS: XR bf16, state_out fp32 ----------------
__global__ __launch_bounds__(256) void reduce_ns(
    const float* __restrict__ Pp, const float* __restrict__ bias,
    short* __restrict__ XRb, float* __restrict__ so, int M, int N, int KS)
{
  __shared__ float rowbuf[256];
  __shared__ float sbuf[16];
  int row = blockIdx.x;
  size_t MN = (size_t)M*N;
  float s = 0.f, s2 = 0.f;
  for (int c = threadIdx.x; c < N; c += 256){
    float v = bias[c];
    for (int ks = 0; ks < KS; ks++) v += Pp[ks*MN + (size_t)row*N + c];
    rowbuf[c] = v; s += v; s2 += v*v;
  }
  block_reduce2(s, s2, sbuf);
  float m = s / N;
  float r = rsqrtf(s2/N - m*m + 1e-5f);
  for (int c = threadIdx.x; c < N; c += 256){
    float v = rowbuf[c];
    XRb[(size_t)row*256 + c] = f2bf(sigf((v-m)*r));
    so[(size_t)row*N + c] = sigf(v);
  }
}

// ---------------- ctx/att1 LN + att2 + effect; reads fused P [2688][384] x 2 slices ----------------
__global__ __launch_bounds__(448) void ctx_att_effect(
    const float* __restrict__ Pc, const float* __restrict__ ctx_b,
    const float* __restrict__ att1_b,
    const float* __restrict__ w2, const float* __restrict__ b2,
    short* __restrict__ tot)
{
  __shared__ float ctxs[7][250];
  __shared__ float att_s[7];
  int fi = blockIdx.x, tid = threadIdx.x;
  int jj = tid >> 6, lane = tid & 63;
  const size_t MN = (size_t)2688*384;
  int row = fi*7 + jj;
  // ctx: LN + relu (cols 0..249)
  float vv[4];
  float s = 0.f, s2 = 0.f;
  #pragma unroll
  for (int t = 0; t < 4; t++){
    int c = lane + t*64;
    float v = 0.f;
    if (c < 250) v = ctx_b[c] + Pc[(size_t)row*384 + c] + Pc[MN + (size_t)row*384 + c];
    vv[t] = v; s += v; s2 += v*v;
  }
  #pragma unroll
  for (int off = 32; off; off >>= 1){ s += __shfl_down(s, off); s2 += __shfl_down(s2, off); }
  s = __shfl(s, 0); s2 = __shfl(s2, 0);
  float m = s*(1.f/250.f);
  float r = rsqrtf(s2*(1.f/250.f) - m*m + 1e-5f);
  #pragma unroll
  for (int t = 0; t < 4; t++){
    int c = lane + t*64;
    if (c < 250) ctxs[jj][c] = fmaxf((vv[t]-m)*r, 0.f);
  }
  // att1: LN + tanh + dot(w2) + sigmoid (cols 256..355)
  float va[2];
  s = 0.f; s2 = 0.f;
  #pragma unroll
  for (int t = 0; t < 2; t++){
    int c = lane + t*64;
    float v = 0.f;
    if (c < 100)
      v = att1_b[c] + Pc[(size_t)row*384 + 256 + c] + Pc[MN + (size_t)row*384 + 256 + c];
    va[t] = v; s += v; s2 += v*v;
  }
  #pragma unroll
  for (int off = 32; off; off >>= 1){ s += __shfl_down(s, off); s2 += __shfl_down(s2, off); }
  s = __shfl(s, 0); s2 = __shfl(s2, 0);
  m = s*0.01f;
  r = rsqrtf(s2*0.01f - m*m + 1e-5f);
  float d = 0.f;
  #pragma unroll
  for (int t = 0; t < 2; t++){
    int c = lane + t*64;
    if (c < 100) d += tanhf((va[t]-m)*r)*w2[c];
  }
  #pragma unroll
  for (int off = 32; off; off >>= 1) d += __shfl_down(d, off);
  if (lane == 0) att_s[jj] = sigf(d + b2[0]);
  __syncthreads();
  for (int h = tid; h < 250; h += 448){
    float sum = 0.f;
    #pragma unroll
    for (int q = 0; q < 7; q++) sum += ctxs[q][h]*att_s[q];
    tot[(size_t)fi*1024 + 256 + h] = f2bf(sum);
  }
}

// ---------------- fused dec_conv1+2: padded LDS strides (72 / 40) ----------------
__global__ __launch_bounds__(256) void dec_conv12_mfma(
    const short* __restrict__ in, const short* __restrict__ Bd1, const float* __restrict__ bias1,
    const short* __restrict__ Bd2, const float* __restrict__ bias2, short* __restrict__ outp)
{
  __shared__ __align__(16) short smem[18*18*40];
  __shared__ float sbuf[16];
  int n = blockIdx.x, tid = threadIdx.x;
  for (int l = tid; l < 1800; l += 256) ((unsigned long long*)smem)[l] = 0ull;
  __syncthreads();
  const short* ip = in + (size_t)n*4096;
  for (int l = tid; l < 1024; l += 256){
    int i4 = l & 15, sb = (l>>4)&7, sa = l>>7;
    *(uint2*)&smem[((sa+1)*10 + (sb+1))*72 + i4*4] = *(const uint2*)&ip[sa*512 + sb*64 + i4*4];
  }
  int wave = tid>>6, ln = tid&15, quad = (tid>>4)&3;
  int pa = wave & 1, pb = wave >> 1;
  bf16x8 bfr1[2][8];
  #pragma unroll
  for (int nt = 0; nt < 2; nt++){
    const short* Brow = Bd1 + (wave*32 + nt*16 + ln)*256;
    #pragma unroll
    for (int ks = 0; ks < 8; ks++)
      bfr1[nt][ks] = *(const bf16x8*)&Brow[ks*32 + quad*8];
  }
  __syncthreads();
  f32x4 z = {0.f,0.f,0.f,0.f};
  f32x4 acc[2][4] = {{z,z,z,z},{z,z,z,z}};
  #pragma unroll
  for (int ks = 0; ks < 8; ks++){
    int tap = ks>>1, ibase = (ks&1)*32 + quad*8;
    int da = tap & 1, db = tap >> 1;
    #pragma unroll
    for (int mt = 0; mt < 4; mt++){
      int p = mt*16 + ln;
      int ta = p>>3, tb = p&7;
      bf16x8 a = *(const bf16x8*)&smem[((ta+da+pa)*10 + (tb+db+pb))*72 + ibase];
      acc[0][mt] = __builtin_amdgcn_mfma_f32_16x16x32_bf16(a, bfr1[0][ks], acc[0][mt],0,0,0);
      acc[1][mt] = __builtin_amdgcn_mfma_f32_16x16x32_bf16(a, bfr1[1][ks], acc[1][mt],0,0,0);
    }
  }
  float s = 0.f, s2 = 0.f;
  #pragma unroll
  for (int nt = 0; nt < 2; nt++){
    float bz = bias1[nt*16 + ln];
    #pragma unroll
    for (int mt = 0; mt < 4; mt++)
      #pragma unroll
      for (int j = 0; j < 4; j++){
        float v = acc[nt][mt][j] + bz;
        acc[nt][mt][j] = v; s += v; s2 += v*v;
      }
  }
  block_reduce2(s, s2, sbuf);
  float m1 = s*(1.f/8192.f);
  float rs1 = rsqrtf(s2*(1.f/8192.f) - m1*m1 + 1e-5f);
  bf16x8 bfr2[4];
  {
    const short* Brow = Bd2 + (wave*16 + ln)*128;
    #pragma unroll
    for (int ks = 0; ks < 4; ks++)
      bfr2[ks] = *(const bf16x8*)&Brow[ks*32 + quad*8];
  }
  for (int l = tid; l < 3240; l += 256) ((unsigned long long*)smem)[l] = 0ull;
  __syncthreads();
  #pragma unroll
  for (int nt = 0; nt < 2; nt++){
    int o = nt*16 + ln;
    #pragma unroll
    for (int mt = 0; mt < 4; mt++)
      #pragma unroll
      for (int j = 0; j < 4; j++){
        int p = mt*16 + quad*4 + j;
        int ta = p>>3, tb = p&7;
        int sa = 2*ta + pa, sb = 2*tb + pb;
        smem[((sa+1)*18 + (sb+1))*40 + o] = f2bf(fmaxf((acc[nt][mt][j]-m1)*rs1, 0.f));
      }
  }
  __syncthreads();
  f32x4 acc2[16] = {z,z,z,z,z,z,z,z,z,z,z,z,z,z,z,z};
  #pragma unroll
  for (int ks = 0; ks < 4; ks++){
    int da = ks & 1, db = ks >> 1;
    #pragma unroll
    for (int mt = 0; mt < 16; mt++){
      int p = mt*16 + ln;
      int ta = p>>4, tb = p&15;
      bf16x8 a = *(const bf16x8*)&smem[((ta+da+pa)*18 + (tb+db+pb))*40 + quad*8];
      acc2[mt] = __builtin_amdgcn_mfma_f32_16x16x32_bf16(a, bfr2[ks], acc2[mt],0,0,0);
    }
  }
  s = 0.f; s2 = 0.f;
  float bz2 = bias2[ln];
  #pragma unroll
  for (int mt = 0; mt < 16; mt++)
    #pragma unroll
    for (int j = 0; j < 4; j++){
      float v = acc2[mt][j] + bz2;
      acc2[mt][j] = v; s += v; s2 += v*v;
    }
  block_reduce2(s, s2, sbuf);
  float m = s*(1.f/16384.f);
  float rs = rsqrtf(s2*(1.f/16384.f) - m*m + 1e-5f);
  short* op = outp + (size_t)n*16384;
  #pragma unroll
  for (int mt = 0; mt < 16; mt++)
    #pragma unroll
    for (int j = 0; j < 4; j++){
      int p = mt*16 + quad*4 + j;
      int ta = p>>4, tb = p&15;
      op[(2*ta+pa)*512 + (2*tb+pb)*16 + ln] = f2bf(fmaxf((acc2[mt][j]-m)*rs, 0.f));
    }
}

// ---------------- dec_conv3 (final bf16 in) ----------------
__global__ __launch_bounds__(256) void dec_conv3_ig(
    const short* __restrict__ in, const float* __restrict__ CWT, const float* __restrict__ bias,
    float* __restrict__ outp)
{
  __shared__ __align__(16) float in_t[9792];   // [sa34][sb18][i16]
  __shared__ __align__(16) float wl[256];
  int bx = blockIdx.x;
  int n = bx >> 1, b0 = (bx & 1) * 32, tb0 = b0 >> 1;
  int tid = threadIdx.x;
  const short* ip = in + (size_t)n*16384;
  for (int l = tid; l < 9792; l += 256){
    int i = l & 15, sb = (l >> 4) % 18, sap = l / 288;
    int sa = sap - 1, sbg = tb0 - 1 + sb;
    float v = 0.f;
    if ((unsigned)sa < 32u && (unsigned)sbg < 32u)
      v = bf2f(ip[sa*512 + sbg*16 + i]);
    in_t[(sap*18 + sb)*16 + i] = v;
  }
  for (int l = tid; l < 256; l += 256) wl[l] = CWT[l];
  __syncthreads();
  float bv = bias[0];
  int bl = tid & 31, ath = tid >> 5;
  int b = b0 + bl;
  int tb = b >> 1, pb = b & 1;
  float* op = outp + (size_t)n*4096;
  #pragma unroll
  for (int j = 0; j < 8; j++){
    int a = ath*8 + j;
    int ta = a >> 1, pa = a & 1;
    float4 s4 = make_float4(0.f,0.f,0.f,0.f);
    #pragma unroll
    for (int db = 0; db < 2; db++){
      int sb = tb + db + (pb ? 0 : -1);
      int sbl = sb - (tb0 - 1);
      #pragma unroll
      for (int da = 0; da < 2; da++){
        int sa = ta + da + (pa ? 0 : -1);
        int sap = sa + 1;
        const float4* A4 = (const float4*)&in_t[(sap*18 + sbl)*16];
        const float4* B4 = (const float4*)&wl[((pb*2+pa)*4 + db*2+da)*16];
        #pragma unroll
        for (int q = 0; q < 4; q++){
          float4 av = A4[q], bw = B4[q];
          s4.x += av.x*bw.x; s4.y += av.y*bw.y;
          s4.z += av.z*bw.z; s4.w += av.w*bw.w;
        }
      }
    }
    op[a*64 + b] = sigf(bv + s4.x + s4.y + s4.z + s4.w);
  }
}

extern "C" void kernel_launch(void* const* d_in, const int* in_sizes, int n_in,
                              void* d_out, int out_size, void* d_ws, size_t ws_size,
                              hipStream_t stream) {
  const float* x      = (const float*)d_in[0];
  const float* state  = (const float*)d_in[1];
  const float* c1w    = (const float*)d_in[2];
  const float* c1b    = (const float*)d_in[3];
  const float* c2w    = (const float*)d_in[4];
  const float* c2b    = (const float*)d_in[5];
  const float* c3w    = (const float*)d_in[6];
  const float* c3b    = (const float*)d_in[7];
  const float* efc_w  = (const float*)d_in[8];
  const float* efc_b  = (const float*)d_in[9];
  const float* renc_w = (const float*)d_in[10];
  const float* renc_b = (const float*)d_in[11];
  const float* core_w = (const float*)d_in[12];
  const float* core_b = (const float*)d_in[13];
  const float* ctx_w  = (const float*)d_in[14];
  const float* ctx_b  = (const float*)d_in[15];
  const float* att1_w = (const float*)d_in[16];
  const float* att1_b = (const float*)d_in[17];
  const float* att2_w = (const float*)d_in[18];
  const float* att2_b = (const float*)d_in[19];
  const float* out_w  = (const float*)d_in[20];
  const float* out_b  = (const float*)d_in[21];
  const float* dfc1_w = (const float*)d_in[22];
  const float* dfc1_b = (const float*)d_in[23];
  const float* dfc2_w = (const float*)d_in[24];
  const float* dfc2_b = (const float*)d_in[25];
  const float* d1w    = (const float*)d_in[26];
  const float* d1b    = (const float*)d_in[27];
  const float* d2w    = (const float*)d_in[28];
  const float* d2b    = (const float*)d_in[29];
  const float* d3w    = (const float*)d_in[30];
  const float* d3b    = (const float*)d_in[31];

  float* wsf = (float*)d_ws;
  size_t o = 0;
  // private split-K partial buffers (disjoint -> merged launches cannot race)
  float* PB_renc   = wsf + o; o += (size_t)8*384*250;
  float* PB_core   = wsf + o; o += (size_t)2*2688*250;
  float* PB_efc    = wsf + o; o += (size_t)8*384*512;
  float* PB_ctxatt = wsf + o; o += (size_t)2*2688*384;
  float* PB_out    = wsf + o; o += (size_t)8*384*250;
  float* PB_dfc1   = wsf + o; o += (size_t)4*384*512;
  float* PB_dfc2   = wsf + o; o += (size_t)384*4096;
  float* CWT3 = wsf + o; o += 256;
  // bf16 buffers (sizes in shorts; offsets in floats)
  short* E1b  = (short*)(wsf + o); o += (size_t)384*16384/2;   // enc1 final; later dec2 final
  short* E2b  = (short*)(wsf + o); o += (size_t)384*8192/2;    // conv2 raw bf16
  short* E3b  = (short*)(wsf + o); o += (size_t)384*4096/2;    // enc3 final; later G2 final
  short* TOTb = (short*)(wsf + o); o += (size_t)384*1024/2;    // [s1|pad|eff|pad|h]
  short* C1b  = (short*)(wsf + o); o += (size_t)2688*256/2;
  short* XRb  = (short*)(wsf + o); o += (size_t)384*256/2;
  short* G1b  = (short*)(wsf + o); o += (size_t)384*512/2;
  short* SBF  = (short*)(wsf + o); o += (size_t)384*256/2;
  short* BtC2 = (short*)(wsf + o); o += 8192/2;
  short* BtC3 = (short*)(wsf + o); o += 32768/2;
  short* BD1  = (short*)(wsf + o); o += 32768/2;
  short* BD2  = (short*)(wsf + o); o += 8192/2;
  short* BT_efc    = (short*)(wsf + o); o += 2097152/2;
  short* BT_renc   = (short*)(wsf + o); o += 64000/2;
  short* BT_core   = (short*)(wsf + o); o += 128000/2;
  short* BT_ctxatt = (short*)(wsf + o); o += 98304/2;   // [384 rows][256]: 0..249 ctx, 256..355 att1
  short* BT_out    = (short*)(wsf + o); o += 256000/2;
  short* BT_dfc1   = (short*)(wsf + o); o += 131072/2;
  short* BT_dfc2   = (short*)(wsf + o); o += 2097152/2;
  short* D2b = E1b;
  short* G2b = E3b;

  float* xout = (float*)d_out;
  float* sout = xout + (size_t)384*4096;

  // 1. prep: weight transposes + folds + state cvt + pad zeroing
  prep_combined<<<1448, 256, 0, stream>>>(
      efc_w, BT_efc, dfc2_w, BT_dfc2, out_w, BT_out, core_w, BT_core,
      dfc1_w, BT_dfc1, renc_w, BT_renc, ctx_w, att1_w, BT_ctxatt,
      d3w, CWT3, c2w, BtC2, c3w, BtC3, d1w, BD1, d2w, BD2, state, SBF, TOTb);

  // 2-6. fused parallel-path stages (enc || state)
  fuse_a<<<576, 256, 0, stream>>>(x, c1w, c1b, E1b, SBF, BT_renc, PB_renc);
  fuse_b<<<1152, 256, 0, stream>>>(PB_renc, renc_b, TOTb, E1b, BtC2, E2b);
  fuse_c<<<720, 256, 0, stream>>>(TOTb, BT_core, PB_core, E2b, c2b, BtC3, c3b, E3b);
  fuse_d<<<3072, 256, 0, stream>>>(PB_core, core_b, C1b, E3b, BT_efc, PB_efc);
  fuse_e<<<888, 256, 0, stream>>>(C1b, BT_ctxatt, PB_ctxatt, PB_efc, efc_b, TOTb+512);

  // 7. attention-weighted effect
  ctx_att_effect<<<384, 448, 0, stream>>>(PB_ctxatt, ctx_b, att1_b, att2_w, att2_b, TOTb);

  // 8-9. combine
  gemm_mfma<<<dim3(4,6,8), 256, 0, stream>>>(TOTb, BT_out, PB_out, 384, 250, 1024, 128);
  reduce_ns<<<384, 256, 0, stream>>>(PB_out, out_b, XRb, sout, 384, 250, 8);

  // 10-13. decoder FC
  gemm_mfma<<<dim3(8,6,4), 256, 0, stream>>>(XRb, BT_dfc1, PB_dfc1, 384, 512, 256, 64);
  reduce_ln<<<384, 256, 0, stream>>>(PB_dfc1, dfc1_b, G1b, 384, 512, 4, 512, 1, 1, -1);
  gemm_mfma<<<dim3(64,6,1), 256, 0, stream>>>(G1b, BT_dfc2, PB_dfc2, 384, 4096, 512, 512);
  reduce_ln<<<384, 256, 0, stream>>>(PB_dfc2, dfc2_b, G2b, 384, 4096, 1, 4096, 1, 1, -1);

  // 14-15. decoder convs
  dec_conv12_mfma<<<384, 256, 0, stream>>>(G2b, BD1, d1b, BD2, d2b, D2b);
  dec_conv3_ig<<<768, 256, 0, stream>>>(D2b, CWT3, d3b, xout);

  (void)in_sizes; (void)n_in; (void)out_size; (void)ws_size;
}

// Round 11
// 288.696 us; speedup vs baseline: 1.1767x; 1.0175x over previous
//
#include <hip/hip_runtime.h>
#include <hip/hip_bf16.h>
#include <math.h>

typedef __attribute__((ext_vector_type(8))) short bf16x8;
typedef __attribute__((ext_vector_type(4))) float f32x4;

__device__ __forceinline__ float eluf(float v){ return v > 0.f ? v : expm1f(v); }
__device__ __forceinline__ float sigf(float v){ return 1.f/(1.f+expf(-v)); }
__device__ __forceinline__ unsigned short f2bf(float f){
  unsigned u = __float_as_uint(f);
  u += 0x7FFFu + ((u >> 16) & 1u);          // round-to-nearest-even
  return (unsigned short)(u >> 16);
}
__device__ __forceinline__ float bf2f(short s){
  return __uint_as_float(((unsigned)(unsigned short)s) << 16);
}

// ---------------- block-wide sum & sumsq reduction ----------------
__device__ __forceinline__ void block_reduce2(float& a, float& b, float* sbuf){
  __syncthreads();
  for (int off = 32; off; off >>= 1){
    a += __shfl_down(a, off);
    b += __shfl_down(b, off);
  }
  int lane = threadIdx.x & 63, w = threadIdx.x >> 6;
  if (lane == 0){ sbuf[2*w] = a; sbuf[2*w+1] = b; }
  __syncthreads();
  if (threadIdx.x == 0){
    int nw = blockDim.x >> 6;
    float sa = 0.f, sb = 0.f;
    for (int i = 0; i < nw; i++){ sa += sbuf[2*i]; sb += sbuf[2*i+1]; }
    sbuf[0] = sa; sbuf[1] = sb;
  }
  __syncthreads();
  a = sbuf[0]; b = sbuf[1];
}

// ---------------- prep helpers ----------------
__device__ __forceinline__ float fold_sum(const float* __restrict__ w, int O, int I,
                                          int o, int i, int pa, int pb, int da, int db){
  float s = 0.f;
  for (int kh = 0; kh < 4; kh++){
    bool inh = (pb==0) ? (db==0 ? (kh==0) : (kh>=1)) : (db==0 ? (kh<=2) : (kh==3));
    if (!inh) continue;
    for (int kw = 0; kw < 4; kw++){
      bool inw = (pa==0) ? (da==0 ? (kw==0) : (kw>=1)) : (da==0 ? (kw<=2) : (kw==3));
      if (!inw) continue;
      s += w[((o*I + i)*4 + kh)*4 + kw];
    }
  }
  return s;
}
__device__ __forceinline__ void fold_elem(const float* __restrict__ w, float* __restrict__ CW,
                                          int O, int I, int l){
  int o = l % O; int q = l / O;
  int da = q & 1, db = (q>>1)&1, pa = (q>>2)&1, pb = (q>>3)&1, i = q>>4;
  CW[(((pb*2+pa)*4 + db*2+da)*I + i)*O + o] = fold_sum(w, O, I, o, i, pa, pb, da, db);
}
__device__ __forceinline__ void cvtc2_elem(const float* __restrict__ w, short* __restrict__ D, int l){
  int i = l & 15, t = (l>>4) & 15, o = l>>8;        // k = t*16 + i
  D[l] = (short)f2bf(w[(o*16 + i)*16 + t]);
}
__device__ __forceinline__ void cvtc3_elem(const float* __restrict__ w, short* __restrict__ D, int l){
  int i = l & 31, t = (l>>5) & 15, o = l>>9;        // k = t*32 + i
  D[l] = (short)f2bf(w[(o*32 + i)*16 + t]);
}
__device__ __forceinline__ void foldd1_elem(const float* __restrict__ w, short* __restrict__ D, int l){
  int i = l & 63, tap = (l>>6)&3, o = (l>>8)&31, ph = l>>13;
  D[l] = (short)f2bf(fold_sum(w, 32, 64, o, i, ph&1, ph>>1, tap&1, tap>>1));
}
__device__ __forceinline__ void foldd2_elem(const float* __restrict__ w, short* __restrict__ D, int l){
  int i = l & 31, tap = (l>>5)&3, o = (l>>7)&15, ph = l>>11;
  D[l] = (short)f2bf(fold_sum(w, 16, 32, o, i, ph&1, ph>>1, tap&1, tap>>1));
}

// ---------------- small weight transposes (modes) + packs; big transposes moved to fuse_b ----------------
__global__ __launch_bounds__(256) void prep_combined(
  const float* __restrict__ outw, short* __restrict__ Dout,
  const float* __restrict__ corew,short* __restrict__ Dcore,
  const float* __restrict__ dfc1, short* __restrict__ Ddfc1,
  const float* __restrict__ renc, short* __restrict__ Drenc,
  const float* __restrict__ ctx,  const float* __restrict__ att1,
  short* __restrict__ Dctxatt,
  const float* __restrict__ d3w, float* __restrict__ CWT3,
  const float* __restrict__ c2w, short* __restrict__ BtC2,
  const float* __restrict__ c3w, short* __restrict__ BtC3,
  const float* __restrict__ d1w, short* __restrict__ BD1,
  const float* __restrict__ d2w, short* __restrict__ BD2,
  const float* __restrict__ state, short* __restrict__ SBF,
  short* __restrict__ TOTb)
{
  int bx = blockIdx.x;
  if (bx >= 168){
    const int F3=256, P2=F3+8192, P3=P2+32768, P4=P3+32768, P5=P4+8192,
              ST=P5+98304, TP=ST+4608, TOTAL=TP+8704;
    for (int l = (bx-168)*256 + threadIdx.x; l < TOTAL; l += 256*256){
      if (l < F3)      fold_elem(d3w, CWT3, 1, 16, l);
      else if (l < P2) cvtc2_elem(c2w, BtC2, l - F3);
      else if (l < P3) cvtc3_elem(c3w, BtC3, l - P2);
      else if (l < P4) foldd1_elem(d1w, BD1, l - P3);
      else if (l < P5) foldd2_elem(d2w, BD2, l - P4);
      else if (l < ST){
        int q = l - P5;             // state -> bf16 [384][256], zero pad
        int n = q >> 8, k = q & 255;
        SBF[q] = (k < 250) ? (short)f2bf(state[n*250 + k]) : (short)0;
      } else if (l < TP){
        int q = l - ST;             // zero TOT pad cols: 250..255, 506..511
        int row = q / 12, cc = q % 12;
        int col = cc < 6 ? 250 + cc : 506 + (cc - 6);
        TOTb[row*1024 + col] = 0;
      } else {
        int q = l - TP;             // zero ctxatt pad rows: 250..255, 356..383
        int r = q >> 8, cc = q & 255;
        int row = r < 6 ? 250 + r : 356 + (r - 6);
        Dctxatt[row*256 + cc] = 0;
      }
    }
    return;
  }
  const float* W; short* D; int K, N, Kp, base, mode = 0;
  if      (bx < 64) { W=outw; D=Dout;  K=1012; N=250;  Kp=1024; base=0;   mode=2; }
  else if (bx < 96) { W=corew;D=Dcore; K=500;  N=250;  Kp=512;  base=64;  mode=1; }
  else if (bx < 128){ W=dfc1; D=Ddfc1; K=250;  N=512;  Kp=256;  base=96;  }
  else if (bx < 144){ W=renc; D=Drenc; K=250;  N=250;  Kp=256;  base=128; }
  else if (bx < 160){ W=ctx;  D=Dctxatt;         K=250; N=250; Kp=256; base=144; }
  else              { W=att1; D=Dctxatt + 65536; K=250; N=100; Kp=256; base=160; }
  int t = bx - base;
  int tpr = Kp >> 6;
  int tk = t % tpr, tn = t / tpr;
  __shared__ short tile[64][65];
  int c = threadIdx.x & 63, r4 = threadIdx.x >> 6;
  int n0 = tn*64, k0 = tk*64;
  #pragma unroll 4
  for (int p = 0; p < 16; p++){
    int r = r4*16 + p;
    int k = k0 + r, n = n0 + c;
    int ksrc = k; bool valid;
    if (mode == 0) valid = (k < K);
    else if (mode == 1){ valid = (k < 250) || (k >= 256 && k < 506); ksrc = k < 256 ? k : k - 6; }
    else { valid = (k < 250) || (k >= 256 && k < 506) || (k >= 512);
           ksrc = k < 256 ? k : (k < 512 ? k - 6 : k - 12); }
    float v = (valid && n < N) ? W[(size_t)ksrc*N + n] : 0.f;
    tile[c][r] = (short)f2bf(v);
  }
  __syncthreads();
  #pragma unroll 4
  for (int p = 0; p < 16; p++){
    int nn = r4*16 + p;
    int n = n0 + nn;
    if (n < N) D[(size_t)n*Kp + k0 + c] = tile[nn][c];
  }
}

// ---------------- big weight transpose body (K==Kp, no remap) ----------------
__device__ __forceinline__ void wtrans_body(
    const float* __restrict__ W, short* __restrict__ D, int K, int N, int t)
{
  int tpr = K >> 6;
  int tk = t % tpr, tn = t / tpr;
  __shared__ short tile[64][65];
  int c = threadIdx.x & 63, r4 = threadIdx.x >> 6;
  int n0 = tn*64, k0 = tk*64;
  #pragma unroll 4
  for (int p = 0; p < 16; p++){
    int r = r4*16 + p;
    int k = k0 + r, n = n0 + c;
    float v = (n < N) ? W[(size_t)k*N + n] : 0.f;
    tile[c][r] = (short)f2bf(v);
  }
  __syncthreads();
  #pragma unroll 4
  for (int p = 0; p < 16; p++){
    int nn = r4*16 + p;
    int n = n0 + nn;
    if (n < N) D[(size_t)n*K + k0 + c] = tile[nn][c];
  }
}

// ---------------- MFMA bf16 split-K GEMM body ----------------
__device__ __forceinline__ void gemm_body(
    const short* __restrict__ Ab, const short* __restrict__ Bt,
    float* __restrict__ P, int M, int N, int Kp, int Kc,
    int bxx, int byy, int bzz)
{
  __shared__ __align__(16) short As[64*32];
  __shared__ __align__(16) short Bs[64*32];
  int tid = threadIdx.x;
  int bm = byy*64, bn = bxx*64;
  int kb = bzz * Kc;
  int kend = kb + Kc;

  int r = tid >> 2, c = tid & 3;
  const short* Arow = Ab + (size_t)(bm + r)*Kp;
  int gn = bn + r;
  bool bval = gn < N;
  const short* Brow = Bt + (size_t)gn*Kp;

  uint4 hA, hB;
  auto load_regs = [&](int k0){
    hA = *(const uint4*)&Arow[k0 + c*8];
    hB = bval ? *(const uint4*)&Brow[k0 + c*8] : make_uint4(0,0,0,0);
  };
  auto write_lds = [&](){
    *(uint4*)&As[r*32 + c*8] = hA;
    *(uint4*)&Bs[r*32 + c*8] = hB;
  };

  int wave = tid >> 6;
  int ln = tid & 15, quad = (tid >> 4) & 3;
  int wr = (wave >> 1) * 32, wc = (wave & 1) * 32;

  f32x4 zero = {0.f, 0.f, 0.f, 0.f};
  f32x4 acc[2][2] = {{zero, zero}, {zero, zero}};

  load_regs(kb);
  write_lds();
  __syncthreads();
  for (int k0 = kb; k0 < kend; k0 += 32){
    int nxt = k0 + 32;
    if (nxt < kend) load_regs(nxt);
    bf16x8 a0 = *(const bf16x8*)&As[(wr +      ln)*32 + quad*8];
    bf16x8 a1 = *(const bf16x8*)&As[(wr + 16 + ln)*32 + quad*8];
    bf16x8 b0 = *(const bf16x8*)&Bs[(wc +      ln)*32 + quad*8];
    bf16x8 b1 = *(const bf16x8*)&Bs[(wc + 16 + ln)*32 + quad*8];
    acc[0][0] = __builtin_amdgcn_mfma_f32_16x16x32_bf16(a0, b0, acc[0][0], 0, 0, 0);
    acc[0][1] = __builtin_amdgcn_mfma_f32_16x16x32_bf16(a0, b1, acc[0][1], 0, 0, 0);
    acc[1][0] = __builtin_amdgcn_mfma_f32_16x16x32_bf16(a1, b0, acc[1][0], 0, 0, 0);
    acc[1][1] = __builtin_amdgcn_mfma_f32_16x16x32_bf16(a1, b1, acc[1][1], 0, 0, 0);
    __syncthreads();
    if (nxt < kend){ write_lds(); __syncthreads(); }
  }

  float* Pout = P + (size_t)bzz*M*N;
  #pragma unroll
  for (int t = 0; t < 2; t++)
    #pragma unroll
    for (int u = 0; u < 2; u++)
      #pragma unroll
      for (int j = 0; j < 4; j++){
        int row = bm + wr + t*16 + quad*4 + j;
        int col = bn + wc + u*16 + ln;
        if (col < N) Pout[(size_t)row*N + col] = acc[t][u][j];
      }
}

__global__ __launch_bounds__(256) void gemm_mfma(
    const short* __restrict__ Ab, const short* __restrict__ Bt,
    float* __restrict__ P, int M, int N, int Kp, int Kc)
{
  gemm_body(Ab, Bt, P, M, N, Kp, Kc, blockIdx.x, blockIdx.y, blockIdx.z);
}

// ---------------- conv2 gather-GEMM body ----------------
__device__ __forceinline__ void conv2g_body(
    const short* __restrict__ In, const short* __restrict__ Bt,
    short* __restrict__ Out, int bxx)
{
  __shared__ __align__(16) short As[128*32];
  __shared__ __align__(16) short Bs[32*32];
  int tid = threadIdx.x;
  int bm = bxx*128;

  int ra = tid >> 1, ca = (tid & 1)*16;
  int gr = bm + ra;
  int n = gr >> 8, pos = gr & 255;
  int oa = pos >> 4, ob = pos & 15;
  const short* ibase = In + (size_t)n*16384;
  int rb = tid >> 2, cb = (tid & 3)*8;
  const short* Brow = Bt + rb*256;
  bool bact = tid < 128;

  uint4 hA0, hA1, hB;
  auto load_regs = [&](int k0){
    #pragma unroll
    for (int h = 0; h < 2; h++){
      int k = k0 + ca + h*8;
      int tap = k >> 4;
      int ai = 2*oa + (tap & 3) - 1, bi = 2*ob + (tap >> 2) - 1;
      bool v = ((unsigned)ai < 32u) && ((unsigned)bi < 32u);
      uint4 tv = v ? *(const uint4*)&ibase[ai*512 + bi*16 + (k & 15)] : make_uint4(0,0,0,0);
      if (h == 0) hA0 = tv; else hA1 = tv;
    }
    if (bact) hB = *(const uint4*)&Brow[k0 + cb];
  };
  auto write_lds = [&](){
    *(uint4*)&As[ra*32 + ca] = hA0;
    *(uint4*)&As[ra*32 + ca + 8] = hA1;
    if (bact) *(uint4*)&Bs[rb*32 + cb] = hB;
  };

  int wave = tid >> 6, ln = tid & 15, quad = (tid >> 4) & 3;
  int wr = wave * 32;

  f32x4 zero = {0.f,0.f,0.f,0.f};
  f32x4 acc[2][2] = {{zero,zero},{zero,zero}};
  load_regs(0); write_lds(); __syncthreads();
  for (int k0 = 0; k0 < 256; k0 += 32){
    int nxt = k0 + 32;
    if (nxt < 256) load_regs(nxt);
    bf16x8 a0 = *(const bf16x8*)&As[(wr +      ln)*32 + quad*8];
    bf16x8 a1 = *(const bf16x8*)&As[(wr + 16 + ln)*32 + quad*8];
    bf16x8 b0 = *(const bf16x8*)&Bs[(     ln)*32 + quad*8];
    bf16x8 b1 = *(const bf16x8*)&Bs[(16 + ln)*32 + quad*8];
    acc[0][0] = __builtin_amdgcn_mfma_f32_16x16x32_bf16(a0, b0, acc[0][0], 0, 0, 0);
    acc[0][1] = __builtin_amdgcn_mfma_f32_16x16x32_bf16(a0, b1, acc[0][1], 0, 0, 0);
    acc[1][0] = __builtin_amdgcn_mfma_f32_16x16x32_bf16(a1, b0, acc[1][0], 0, 0, 0);
    acc[1][1] = __builtin_amdgcn_mfma_f32_16x16x32_bf16(a1, b1, acc[1][1], 0, 0, 0);
    __syncthreads();
    if (nxt < 256){ write_lds(); __syncthreads(); }
  }
  #pragma unroll
  for (int t = 0; t < 2; t++)
    #pragma unroll
    for (int u = 0; u < 2; u++)
      #pragma unroll
      for (int j = 0; j < 4; j++){
        int row = bm + wr + t*16 + quad*4 + j;
        int col = u*16 + ln;
        Out[(size_t)row*32 + col] = (short)f2bf(acc[t][u][j]);
      }
}

// ---------------- fused enc conv3 body: LN2+ELU + conv3 MFMA + LN3+ELU ----------------
__device__ __forceinline__ void conv3_full_body(
    const short* __restrict__ E2raw, const float* __restrict__ bias2,
    const short* __restrict__ Bt3, const float* __restrict__ bias3,
    short* __restrict__ outp, int n)
{
  __shared__ __align__(16) short lsamp[18*18*40];
  __shared__ float sbuf[16];
  int tid = threadIdx.x;
  const short* ip = E2raw + (size_t)n*8192;
  float vv[32];
  float s = 0.f, s2 = 0.f;
  #pragma unroll
  for (int t = 0; t < 4; t++){
    bf16x8 v8 = *(const bf16x8*)&ip[(t*256 + tid)*8];
    #pragma unroll
    for (int j = 0; j < 8; j++){
      int e = (t*256 + tid)*8 + j;
      float v = bf2f(v8[j]) + bias2[e & 31];
      vv[t*8+j] = v; s += v; s2 += v*v;
    }
  }
  block_reduce2(s, s2, sbuf);
  float m2 = s*(1.f/8192.f);
  float rs2 = rsqrtf(s2*(1.f/8192.f) - m2*m2 + 1e-5f);
  for (int l = tid; l < 18*18*40/4; l += 256) ((unsigned long long*)lsamp)[l] = 0ull;
  __syncthreads();
  #pragma unroll
  for (int t = 0; t < 4; t++){
    int e0 = (t*256 + tid)*8;
    int slot = e0 >> 5, ch0 = e0 & 31;
    int a = slot >> 4, b = slot & 15;
    bf16x8 o8;
    #pragma unroll
    for (int j = 0; j < 8; j++)
      o8[j] = (short)f2bf(eluf((vv[t*8+j]-m2)*rs2));
    *(bf16x8*)&lsamp[((a+1)*18 + (b+1))*40 + ch0] = o8;
  }
  int wave = tid>>6, ln = tid&15, quad = (tid>>4)&3;
  int o3 = wave*16 + ln;
  bf16x8 bfr3[16];
  {
    const short* Brow = Bt3 + o3*512;
    #pragma unroll
    for (int ks = 0; ks < 16; ks++)
      bfr3[ks] = *(const bf16x8*)&Brow[ks*32 + quad*8];
  }
  __syncthreads();
  f32x4 z = {0.f,0.f,0.f,0.f};
  f32x4 acc3[4] = {z,z,z,z};
  #pragma unroll
  for (int ks = 0; ks < 16; ks++){
    int kh = ks>>2, kw = ks&3;
    #pragma unroll
    for (int mt = 0; mt < 4; mt++){
      int p = mt*16 + ln;
      int oa = p>>3, ob = p&7;
      bf16x8 a = *(const bf16x8*)&lsamp[((2*oa+kw)*18 + (2*ob+kh))*40 + quad*8];
      acc3[mt] = __builtin_amdgcn_mfma_f32_16x16x32_bf16(a, bfr3[ks], acc3[mt],0,0,0);
    }
  }
  s = 0.f; s2 = 0.f;
  float bz3 = bias3[o3];
  #pragma unroll
  for (int mt = 0; mt < 4; mt++)
    #pragma unroll
    for (int j = 0; j < 4; j++){
      float v = acc3[mt][j] + bz3;
      acc3[mt][j] = v; s += v; s2 += v*v;
    }
  block_reduce2(s, s2, sbuf);
  float m3 = s*(1.f/4096.f);
  float rs3 = rsqrtf(s2*(1.f/4096.f) - m3*m3 + 1e-5f);
  short* op = outp + (size_t)n*4096;
  #pragma unroll
  for (int mt = 0; mt < 4; mt++)
    #pragma unroll
    for (int j = 0; j < 4; j++){
      int p = mt*16 + quad*4 + j;
      int oa = p>>3, ob = p&7;
      op[oa*512 + ob*64 + o3] = f2bf(eluf((acc3[mt][j]-m3)*rs3));
    }
}

// ---------------- core GEMM body (A gathered from padded TOT) ----------------
__device__ __forceinline__ void gemm_core_body(
    const short* __restrict__ Tb, const short* __restrict__ Bt,
    float* __restrict__ P, int M, int N, int Kc,
    int bxx, int byy, int bzz)
{
  __shared__ __align__(16) short As[64*32];
  __shared__ __align__(16) short Bs[64*32];
  int tid = threadIdx.x;
  int bm = byy*64, bn = bxx*64;
  int kb = bzz * Kc;
  int kend = kb + Kc;

  int r = tid >> 2, c = tid & 3;
  int gr = bm + r;
  int jj2 = gr % 7, fi2 = gr / 7;
  int ii = fi2 & 7, j2 = fi2 >> 3;
  int jidx = jj2 < ii ? jj2 : jj2 + 1;
  const short* own = Tb + (size_t)fi2*1024;
  const short* oth = Tb + (size_t)(j2*8 + jidx)*1024;
  int gn = bn + r;
  bool bval = gn < N;
  const short* Brow = Bt + (size_t)gn*512;

  uint4 hA, hB;
  auto load_regs = [&](int k0){
    int kk = k0 + c*8;
    const short* src = (kk & 256) ? oth : own;
    hA = *(const uint4*)&src[kk & 255];
    hB = bval ? *(const uint4*)&Brow[kk] : make_uint4(0,0,0,0);
  };
  auto write_lds = [&](){
    *(uint4*)&As[r*32 + c*8] = hA;
    *(uint4*)&Bs[r*32 + c*8] = hB;
  };

  int wave = tid >> 6;
  int ln = tid & 15, quad = (tid >> 4) & 3;
  int wr = (wave >> 1) * 32, wc = (wave & 1) * 32;

  f32x4 zero = {0.f, 0.f, 0.f, 0.f};
  f32x4 acc[2][2] = {{zero, zero}, {zero, zero}};

  load_regs(kb);
  write_lds();
  __syncthreads();
  for (int k0 = kb; k0 < kend; k0 += 32){
    int nxt = k0 + 32;
    if (nxt < kend) load_regs(nxt);
    bf16x8 a0 = *(const bf16x8*)&As[(wr +      ln)*32 + quad*8];
    bf16x8 a1 = *(const bf16x8*)&As[(wr + 16 + ln)*32 + quad*8];
    bf16x8 b0 = *(const bf16x8*)&Bs[(wc +      ln)*32 + quad*8];
    bf16x8 b1 = *(const bf16x8*)&Bs[(wc + 16 + ln)*32 + quad*8];
    acc[0][0] = __builtin_amdgcn_mfma_f32_16x16x32_bf16(a0, b0, acc[0][0], 0, 0, 0);
    acc[0][1] = __builtin_amdgcn_mfma_f32_16x16x32_bf16(a0, b1, acc[0][1], 0, 0, 0);
    acc[1][0] = __builtin_amdgcn_mfma_f32_16x16x32_bf16(a1, b0, acc[1][0], 0, 0, 0);
    acc[1][1] = __builtin_amdgcn_mfma_f32_16x16x32_bf16(a1, b1, acc[1][1], 0, 0, 0);
    __syncthreads();
    if (nxt < kend){ write_lds(); __syncthreads(); }
  }

  float* Pout = P + (size_t)bzz*M*N;
  #pragma unroll
  for (int t = 0; t < 2; t++)
    #pragma unroll
    for (int u = 0; u < 2; u++)
      #pragma unroll
      for (int j = 0; j < 4; j++){
        int row = bm + wr + t*16 + quad*4 + j;
        int col = bn + wc + u*16 + ln;
        if (col < N) Pout[(size_t)row*N + col] = acc[t][u][j];
      }
}

// ---------------- reduce_ln body ----------------
__device__ __forceinline__ void reduce_ln_body(
    const float* __restrict__ Pp, const float* __restrict__ bias,
    void* __restrict__ outp, int M, int N, int KS, int os, int act, int obf, int bmask,
    int row)
{
  __shared__ float rowbuf[4096];
  __shared__ float sbuf[16];
  size_t MN = (size_t)M*N;
  float s = 0.f, s2 = 0.f;
  for (int c = threadIdx.x; c < N; c += 256){
    float v = bias[c & bmask];
    for (int ks = 0; ks < KS; ks++) v += Pp[ks*MN + (size_t)row*N + c];
    rowbuf[c] = v; s += v; s2 += v*v;
  }
  block_reduce2(s, s2, sbuf);
  float m = s / N;
  float r = rsqrtf(s2/N - m*m + 1e-5f);
  for (int c = threadIdx.x; c < N; c += 256){
    float v = (rowbuf[c]-m)*r;
    if (act == 1) v = fmaxf(v, 0.f);
    else if (act == 2) v = eluf(v);
    else if (act == 3) v = tanhf(v);
    if (obf) ((short*)outp)[(size_t)row*os + c] = f2bf(v);
    else     ((float*)outp)[(size_t)row*os + c] = v;
  }
}

__global__ __launch_bounds__(256) void reduce_ln(
    const float* __restrict__ Pp, const float* __restrict__ bias,
    void* __restrict__ outp, int M, int N, int KS, int os, int act, int obf, int bmask)
{
  reduce_ln_body(Pp, bias, outp, M, N, KS, os, act, obf, bmask, blockIdx.x);
}

// ---------------- enc_conv1 body ----------------
__device__ __forceinline__ void enc_conv1_body(
    const float* __restrict__ x, const float* __restrict__ w, const float* __restrict__ bias,
    short* __restrict__ outp, int n)
{
  __shared__ __align__(16) float in_t[66*68];
  __shared__ short rawb[16384];
  __shared__ float sbuf[16];
  int tid = threadIdx.x;
  for (int l = tid; l < 66*68; l += 256) in_t[l] = 0.f;
  __syncthreads();
  const float* xin = x + (size_t)n*4096;
  for (int l4 = tid; l4 < 1024; l4 += 256){
    float4 v = *(const float4*)&xin[l4*4];
    int aa = (l4*4) >> 6, bb = (l4*4) & 63;
    float* dst = &in_t[(aa+1)*68 + bb + 1];
    dst[0]=v.x; dst[1]=v.y; dst[2]=v.z; dst[3]=v.w;
  }
  int o = tid & 15;
  float wr[16];
  #pragma unroll
  for (int t = 0; t < 16; t++) wr[t] = w[o*16 + t];
  float bv = bias[o];
  __syncthreads();
  float s = 0.f, s2 = 0.f;
  for (int r = 0; r < 64; r++){
    int idx = tid + (r<<8);
    int bq = (idx>>4)&31, aq = idx>>9;
    int a0 = 2*aq, b0 = 2*bq;
    float acc = bv;
    #pragma unroll
    for (int kw = 0; kw < 4; kw++){
      const float* row = &in_t[(a0+kw)*68 + b0];
      float2 p0 = *(const float2*)&row[0];
      float2 p1 = *(const float2*)&row[2];
      acc += p0.x*wr[0*4+kw] + p0.y*wr[1*4+kw] + p1.x*wr[2*4+kw] + p1.y*wr[3*4+kw];
    }
    rawb[idx] = f2bf(acc);
    s += acc; s2 += acc*acc;
  }
  block_reduce2(s, s2, sbuf);
  float m = s*(1.f/16384.f);
  float rs = rsqrtf(s2*(1.f/16384.f) - m*m + 1e-5f);
  short* op = outp + (size_t)n*16384;
  for (int l = tid; l < 16384; l += 256){
    float v = bf2f(rawb[l]);
    op[l] = f2bf(eluf((v-m)*rs));
  }
}

// ---------------- fused parallel-path launches ----------------
// F_a: enc_conv1 [0,384) || renc GEMM [384,576)
__global__ __launch_bounds__(256) void fuse_a(
    const float* __restrict__ x, const float* __restrict__ c1w, const float* __restrict__ c1b,
    short* __restrict__ E1b,
    const short* __restrict__ SBF, const short* __restrict__ BT_renc, float* __restrict__ PB_renc)
{
  int b = blockIdx.x;
  if (b < 384){
    enc_conv1_body(x, c1w, c1b, E1b, b);
  } else {
    int id = b - 384;                       // dim3(4,6,8)
    gemm_body(SBF, BT_renc, PB_renc, 384, 250, 256, 32, id & 3, (id >> 2) % 6, id / 24);
  }
}

// F_b: renc LN [0,384) || conv2 GEMM [384,1152) || big transposes [1152,2176)
__global__ __launch_bounds__(256) void fuse_b(
    const float* __restrict__ PB_renc, const float* __restrict__ renc_b, short* __restrict__ TOTb,
    const short* __restrict__ E1b, const short* __restrict__ BtC2, short* __restrict__ E2b,
    const float* __restrict__ efc_w, short* __restrict__ BT_efc,
    const float* __restrict__ dfc2_w, short* __restrict__ BT_dfc2)
{
  int b = blockIdx.x;
  if (b < 384){
    reduce_ln_body(PB_renc, renc_b, TOTb, 384, 250, 8, 1024, 1, 1, -1, b);
  } else if (b < 1152){
    conv2g_body(E1b, BtC2, E2b, b - 384);
  } else {
    int id = b - 1152;
    if (id < 512) wtrans_body(efc_w, BT_efc, 4096, 512, id);
    else          wtrans_body(dfc2_w, BT_dfc2, 512, 4096, id - 512);
  }
}

// F_c: core GEMM [0,336) || conv3_full [336,720)
__global__ __launch_bounds__(256) void fuse_c(
    const short* __restrict__ TOTb, const short* __restrict__ BT_core, float* __restrict__ PB_core,
    const short* __restrict__ E2b, const float* __restrict__ c2b,
    const short* __restrict__ BtC3, const float* __restrict__ c3b, short* __restrict__ E3b)
{
  int b = blockIdx.x;
  if (b < 336){                             // dim3(4,42,2)
    gemm_core_body(TOTb, BT_core, PB_core, 2688, 250, 256, b % 4, (b / 4) % 42, b / 168);
  } else {
    conv3_full_body(E2b, c2b, BtC3, c3b, E3b, b - 336);
  }
}

// F_d: core LN [0,2688) || efc GEMM [2688,3072)
__global__ __launch_bounds__(256) void fuse_d(
    const float* __restrict__ PB_core, const float* __restrict__ core_b, short* __restrict__ C1b,
    const short* __restrict__ E3b, const short* __restrict__ BT_efc, float* __restrict__ PB_efc)
{
  int b = blockIdx.x;
  if (b < 2688){
    reduce_ln_body(PB_core, core_b, C1b, 2688, 250, 2, 256, 1, 1, -1, b);
  } else {
    int id = b - 2688;                      // dim3(8,6,8)
    gemm_body(E3b, BT_efc, PB_efc, 384, 512, 4096, 512, id & 7, (id >> 3) % 6, id / 48);
  }
}

// F_e: ctxatt GEMM [0,504) || efc LN [504,888)
__global__ __launch_bounds__(256) void fuse_e(
    const short* __restrict__ C1b, const short* __restrict__ BT_ctxatt, float* __restrict__ PB_ctxatt,
    const float* __restrict__ PB_efc, const float* __restrict__ efc_b, short* __restrict__ TOTh)
{
  int b = blockIdx.x;
  if (b < 504){                             // dim3(6,42,2)
    gemm_body(C1b, BT_ctxatt, PB_ctxatt, 2688, 384, 256, 128, b % 6, (b / 6) % 42, b / 252);
  } else {
    reduce_ln_body(PB_efc, efc_b, TOTh, 384, 512, 8, 1024, 2, 1, -1, b - 504);
  }
}

// ---------------- fused NS: XR bf16, state_out fp32 ----------------
__global__ __launch_bounds__(256) void reduce_ns(
    const float* __restrict__ Pp, const float* __restrict__ bias,
    short* __restrict__ XRb, float* __restrict__ so, int M, int N, int KS)
{
  __shared__ float rowbuf[256];
  __shared__ float sbuf[16];
  int row = blockIdx.x;
  size_t MN = (size_t)M*N;
  float s = 0.f, s2 = 0.f;
  for (int c = threadIdx.x; c < N; c += 256){
    float v = bias[c];
    for (int ks = 0; ks < KS; ks++) v += Pp[ks*MN + (size_t)row*N + c];
    rowbuf[c] = v; s += v; s2 += v*v;
  }
  block_reduce2(s, s2, sbuf);
  float m = s / N;
  float r = rsqrtf(s2/N - m*m + 1e-5f);
  for (int c = threadIdx.x; c < N; c += 256){
    float v = rowbuf[c];
    XRb[(size_t)row*256 + c] = f2bf(sigf((v-m)*r));
    so[(size_t)row*N + c] = sigf(v);
  }
}

// ---------------- ctx/att1 LN + att2 + effect; reads fused P [2688][384] x 2 slices ----------------
__global__ __launch_bounds__(448) void ctx_att_effect(
    const float* __restrict__ Pc, const float* __restrict__ ctx_b,
    const float* __restrict__ att1_b,
    const float* __restrict__ w2, const float* __restrict__ b2,
    short* __restrict__ tot)
{
  __shared__ float ctxs[7][250];
  __shared__ float att_s[7];
  int fi = blockIdx.x, tid = threadIdx.x;
  int jj = tid >> 6, lane = tid & 63;
  const size_t MN = (size_t)2688*384;
  int row = fi*7 + jj;
  // ctx: LN + relu (cols 0..249)
  float vv[4];
  float s = 0.f, s2 = 0.f;
  #pragma unroll
  for (int t = 0; t < 4; t++){
    int c = lane + t*64;
    float v = 0.f;
    if (c < 250) v = ctx_b[c] + Pc[(size_t)row*384 + c] + Pc[MN + (size_t)row*384 + c];
    vv[t] = v; s += v; s2 += v*v;
  }
  #pragma unroll
  for (int off = 32; off; off >>= 1){ s += __shfl_down(s, off); s2 += __shfl_down(s2, off); }
  s = __shfl(s, 0); s2 = __shfl(s2, 0);
  float m = s*(1.f/250.f);
  float r = rsqrtf(s2*(1.f/250.f) - m*m + 1e-5f);
  #pragma unroll
  for (int t = 0; t < 4; t++){
    int c = lane + t*64;
    if (c < 250) ctxs[jj][c] = fmaxf((vv[t]-m)*r, 0.f);
  }
  // att1: LN + tanh + dot(w2) + sigmoid (cols 256..355)
  float va[2];
  s = 0.f; s2 = 0.f;
  #pragma unroll
  for (int t = 0; t < 2; t++){
    int c = lane + t*64;
    float v = 0.f;
    if (c < 100)
      v = att1_b[c] + Pc[(size_t)row*384 + 256 + c] + Pc[MN + (size_t)row*384 + 256 + c];
    va[t] = v; s += v; s2 += v*v;
  }
  #pragma unroll
  for (int off = 32; off; off >>= 1){ s += __shfl_down(s, off); s2 += __shfl_down(s2, off); }
  s = __shfl(s, 0); s2 = __shfl(s2, 0);
  m = s*0.01f;
  r = rsqrtf(s2*0.01f - m*m + 1e-5f);
  float d = 0.f;
  #pragma unroll
  for (int t = 0; t < 2; t++){
    int c = lane + t*64;
    if (c < 100) d += tanhf((va[t]-m)*r)*w2[c];
  }
  #pragma unroll
  for (int off = 32; off; off >>= 1) d += __shfl_down(d, off);
  if (lane == 0) att_s[jj] = sigf(d + b2[0]);
  __syncthreads();
  for (int h = tid; h < 250; h += 448){
    float sum = 0.f;
    #pragma unroll
    for (int q = 0; q < 7; q++) sum += ctxs[q][h]*att_s[q];
    tot[(size_t)fi*1024 + 256 + h] = f2bf(sum);
  }
}

// ---------------- fused dfc2-LN + dec_conv1+2 (block n = sample n) ----------------
__global__ __launch_bounds__(256) void dec_ln_conv12(
    const float* __restrict__ Pp, const float* __restrict__ biasln,
    const short* __restrict__ Bd1, const float* __restrict__ bias1,
    const short* __restrict__ Bd2, const float* __restrict__ bias2, short* __restrict__ outp)
{
  __shared__ __align__(16) short smem[18*18*40];
  __shared__ float sbuf[16];
  int n = blockIdx.x, tid = threadIdx.x;
  // --- LN over dfc2 row n (4096, KS=1) kept in registers ---
  const float* Prow = Pp + (size_t)n*4096;
  float vln[16];
  float sl = 0.f, sl2 = 0.f;
  #pragma unroll
  for (int k = 0; k < 16; k++){
    int c = k*256 + tid;
    float v = biasln[c] + Prow[c];
    vln[k] = v; sl += v; sl2 += v*v;
  }
  block_reduce2(sl, sl2, sbuf);
  float ml = sl*(1.f/4096.f);
  float rl = rsqrtf(sl2*(1.f/4096.f) - ml*ml + 1e-5f);
  // --- zero conv1 staging, scatter activated LN output (same bytes as old G2b) ---
  for (int l = tid; l < 1800; l += 256) ((unsigned long long*)smem)[l] = 0ull;   // 7200 shorts
  __syncthreads();
  #pragma unroll
  for (int k = 0; k < 16; k++){
    int c = k*256 + tid;
    int sa = c >> 9, sb = (c >> 6) & 7, i = c & 63;
    smem[((sa+1)*10 + (sb+1))*72 + i] = (short)f2bf(fmaxf((vln[k]-ml)*rl, 0.f));
  }
  int wave = tid>>6, ln = tid&15, quad = (tid>>4)&3;
  int pa = wave & 1, pb = wave >> 1;
  bf16x8 bfr1[2][8];
  #pragma unroll
  for (int nt = 0; nt < 2; nt++){
    const short* Brow = Bd1 + (wave*32 + nt*16 + ln)*256;
    #pragma unroll
    for (int ks = 0; ks < 8; ks++)
      bfr1[nt][ks] = *(const bf16x8*)&Brow[ks*32 + quad*8];
  }
  __syncthreads();
  f32x4 z = {0.f,0.f,0.f,0.f};
  f32x4 acc[2][4] = {{z,z,z,z},{z,z,z,z}};
  #pragma unroll
  for (int ks = 0; ks < 8; ks++){
    int tap = ks>>1, ibase = (ks&1)*32 + quad*8;
    int da = tap & 1, db = tap >> 1;
    #pragma unroll
    for (int mt = 0; mt < 4; mt++){
      int p = mt*16 + ln;
      int ta = p>>3, tb = p&7;
      bf16x8 a = *(const bf16x8*)&smem[((ta+da+pa)*10 + (tb+db+pb))*72 + ibase];
      acc[0][mt] = __builtin_amdgcn_mfma_f32_16x16x32_bf16(a, bfr1[0][ks], acc[0][mt],0,0,0);
      acc[1][mt] = __builtin_amdgcn_mfma_f32_16x16x32_bf16(a, bfr1[1][ks], acc[1][mt],0,0,0);
    }
  }
  float s = 0.f, s2 = 0.f;
  #pragma unroll
  for (int nt = 0; nt < 2; nt++){
    float bz = bias1[nt*16 + ln];
    #pragma unroll
    for (int mt = 0; mt < 4; mt++)
      #pragma unroll
      for (int j = 0; j < 4; j++){
        float v = acc[nt][mt][j] + bz;
        acc[nt][mt][j] = v; s += v; s2 += v*v;
      }
  }
  block_reduce2(s, s2, sbuf);   // final barrier also guards smem reuse
  float m1 = s*(1.f/8192.f);
  float rs1 = rsqrtf(s2*(1.f/8192.f) - m1*m1 + 1e-5f);
  bf16x8 bfr2[4];
  {
    const short* Brow = Bd2 + (wave*16 + ln)*128;
    #pragma unroll
    for (int ks = 0; ks < 4; ks++)
      bfr2[ks] = *(const bf16x8*)&Brow[ks*32 + quad*8];
  }
  for (int l = tid; l < 3240; l += 256) ((unsigned long long*)smem)[l] = 0ull;   // 12960 shorts
  __syncthreads();
  #pragma unroll
  for (int nt = 0; nt < 2; nt++){
    int o = nt*16 + ln;
    #pragma unroll
    for (int mt = 0; mt < 4; mt++)
      #pragma unroll
      for (int j = 0; j < 4; j++){
        int p = mt*16 + quad*4 + j;
        int ta = p>>3, tb = p&7;
        int sa = 2*ta + pa, sb = 2*tb + pb;
        smem[((sa+1)*18 + (sb+1))*40 + o] = f2bf(fmaxf((acc[nt][mt][j]-m1)*rs1, 0.f));
      }
  }
  __syncthreads();
  f32x4 acc2[16] = {z,z,z,z,z,z,z,z,z,z,z,z,z,z,z,z};
  #pragma unroll
  for (int ks = 0; ks < 4; ks++){
    int da = ks & 1, db = ks >> 1;
    #pragma unroll
    for (int mt = 0; mt < 16; mt++){
      int p = mt*16 + ln;
      int ta = p>>4, tb = p&15;
      bf16x8 a = *(const bf16x8*)&smem[((ta+da+pa)*18 + (tb+db+pb))*40 + quad*8];
      acc2[mt] = __builtin_amdgcn_mfma_f32_16x16x32_bf16(a, bfr2[ks], acc2[mt],0,0,0);
    }
  }
  s = 0.f; s2 = 0.f;
  float bz2 = bias2[ln];
  #pragma unroll
  for (int mt = 0; mt < 16; mt++)
    #pragma unroll
    for (int j = 0; j < 4; j++){
      float v = acc2[mt][j] + bz2;
      acc2[mt][j] = v; s += v; s2 += v*v;
    }
  block_reduce2(s, s2, sbuf);
  float m = s*(1.f/16384.f);
  float rs = rsqrtf(s2*(1.f/16384.f) - m*m + 1e-5f);
  short* op = outp + (size_t)n*16384;
  #pragma unroll
  for (int mt = 0; mt < 16; mt++)
    #pragma unroll
    for (int j = 0; j < 4; j++){
      int p = mt*16 + quad*4 + j;
      int ta = p>>4, tb = p&15;
      op[(2*ta+pa)*512 + (2*tb+pb)*16 + ln] = f2bf(fmaxf((acc2[mt][j]-m)*rs, 0.f));
    }
}

// ---------------- dec_conv3 (final bf16 in) ----------------
__global__ __launch_bounds__(256) void dec_conv3_ig(
    const short* __restrict__ in, const float* __restrict__ CWT, const float* __restrict__ bias,
    float* __restrict__ outp)
{
  __shared__ __align__(16) float in_t[9792];   // [sa34][sb18][i16]
  __shared__ __align__(16) float wl[256];
  int bx = blockIdx.x;
  int n = bx >> 1, b0 = (bx & 1) * 32, tb0 = b0 >> 1;
  int tid = threadIdx.x;
  const short* ip = in + (size_t)n*16384;
  for (int l = tid; l < 9792; l += 256){
    int i = l & 15, sb = (l >> 4) % 18, sap = l / 288;
    int sa = sap - 1, sbg = tb0 - 1 + sb;
    float v = 0.f;
    if ((unsigned)sa < 32u && (unsigned)sbg < 32u)
      v = bf2f(ip[sa*512 + sbg*16 + i]);
    in_t[(sap*18 + sb)*16 + i] = v;
  }
  for (int l = tid; l < 256; l += 256) wl[l] = CWT[l];
  __syncthreads();
  float bv = bias[0];
  int bl = tid & 31, ath = tid >> 5;
  int b = b0 + bl;
  int tb = b >> 1, pb = b & 1;
  float* op = outp + (size_t)n*4096;
  #pragma unroll
  for (int j = 0; j < 8; j++){
    int a = ath*8 + j;
    int ta = a >> 1, pa = a & 1;
    float4 s4 = make_float4(0.f,0.f,0.f,0.f);
    #pragma unroll
    for (int db = 0; db < 2; db++){
      int sb = tb + db + (pb ? 0 : -1);
      int sbl = sb - (tb0 - 1);
      #pragma unroll
      for (int da = 0; da < 2; da++){
        int sa = ta + da + (pa ? 0 : -1);
        int sap = sa + 1;
        const float4* A4 = (const float4*)&in_t[(sap*18 + sbl)*16];
        const float4* B4 = (const float4*)&wl[((pb*2+pa)*4 + db*2+da)*16];
        #pragma unroll
        for (int q = 0; q < 4; q++){
          float4 av = A4[q], bw = B4[q];
          s4.x += av.x*bw.x; s4.y += av.y*bw.y;
          s4.z += av.z*bw.z; s4.w += av.w*bw.w;
        }
      }
    }
    op[a*64 + b] = sigf(bv + s4.x + s4.y + s4.z + s4.w);
  }
}

extern "C" void kernel_launch(void* const* d_in, const int* in_sizes, int n_in,
                              void* d_out, int out_size, void* d_ws, size_t ws_size,
                              hipStream_t stream) {
  const float* x      = (const float*)d_in[0];
  const float* state  = (const float*)d_in[1];
  const float* c1w    = (const float*)d_in[2];
  const float* c1b    = (const float*)d_in[3];
  const float* c2w    = (const float*)d_in[4];
  const float* c2b    = (const float*)d_in[5];
  const float* c3w    = (const float*)d_in[6];
  const float* c3b    = (const float*)d_in[7];
  const float* efc_w  = (const float*)d_in[8];
  const float* efc_b  = (const float*)d_in[9];
  const float* renc_w = (const float*)d_in[10];
  const float* renc_b = (const float*)d_in[11];
  const float* core_w = (const float*)d_in[12];
  const float* core_b = (const float*)d_in[13];
  const float* ctx_w  = (const float*)d_in[14];
  const float* ctx_b  = (const float*)d_in[15];
  const float* att1_w = (const float*)d_in[16];
  const float* att1_b = (const float*)d_in[17];
  const float* att2_w = (const float*)d_in[18];
  const float* att2_b = (const float*)d_in[19];
  const float* out_w  = (const float*)d_in[20];
  const float* out_b  = (const float*)d_in[21];
  const float* dfc1_w = (const float*)d_in[22];
  const float* dfc1_b = (const float*)d_in[23];
  const float* dfc2_w = (const float*)d_in[24];
  const float* dfc2_b = (const float*)d_in[25];
  const float* d1w    = (const float*)d_in[26];
  const float* d1b    = (const float*)d_in[27];
  const float* d2w    = (const float*)d_in[28];
  const float* d2b    = (const float*)d_in[29];
  const float* d3w    = (const float*)d_in[30];
  const float* d3b    = (const float*)d_in[31];

  float* wsf = (float*)d_ws;
  size_t o = 0;
  // private split-K partial buffers (disjoint -> merged launches cannot race)
  float* PB_renc   = wsf + o; o += (size_t)8*384*250;
  float* PB_core   = wsf + o; o += (size_t)2*2688*250;
  float* PB_efc    = wsf + o; o += (size_t)8*384*512;
  float* PB_ctxatt = wsf + o; o += (size_t)2*2688*384;
  float* PB_out    = wsf + o; o += (size_t)8*384*250;
  float* PB_dfc1   = wsf + o; o += (size_t)4*384*512;
  float* PB_dfc2   = wsf + o; o += (size_t)384*4096;
  float* CWT3 = wsf + o; o += 256;
  // bf16 buffers (sizes in shorts; offsets in floats)
  short* E1b  = (short*)(wsf + o); o += (size_t)384*16384/2;   // enc1 final; later dec2 final
  short* E2b  = (short*)(wsf + o); o += (size_t)384*8192/2;    // conv2 raw bf16
  short* E3b  = (short*)(wsf + o); o += (size_t)384*4096/2;    // enc3 final
  short* TOTb = (short*)(wsf + o); o += (size_t)384*1024/2;    // [s1|pad|eff|pad|h]
  short* C1b  = (short*)(wsf + o); o += (size_t)2688*256/2;
  short* XRb  = (short*)(wsf + o); o += (size_t)384*256/2;
  short* G1b  = (short*)(wsf + o); o += (size_t)384*512/2;
  short* SBF  = (short*)(wsf + o); o += (size_t)384*256/2;
  short* BtC2 = (short*)(wsf + o); o += 8192/2;
  short* BtC3 = (short*)(wsf + o); o += 32768/2;
  short* BD1  = (short*)(wsf + o); o += 32768/2;
  short* BD2  = (short*)(wsf + o); o += 8192/2;
  short* BT_efc    = (short*)(wsf + o); o += 2097152/2;
  short* BT_renc   = (short*)(wsf + o); o += 64000/2;
  short* BT_core   = (short*)(wsf + o); o += 128000/2;
  short* BT_ctxatt = (short*)(wsf + o); o += 98304/2;   // [384 rows][256]: 0..249 ctx, 256..355 att1
  short* BT_out    = (short*)(wsf + o); o += 256000/2;
  short* BT_dfc1   = (short*)(wsf + o); o += 131072/2;
  short* BT_dfc2   = (short*)(wsf + o); o += 2097152/2;
  short* D2b = E1b;

  float* xout = (float*)d_out;
  float* sout = xout + (size_t)384*4096;

  // 1. prep (small transposes + folds + state cvt + pad zeroing); big transposes moved to fuse_b
  prep_combined<<<424, 256, 0, stream>>>(
      out_w, BT_out, core_w, BT_core, dfc1_w, BT_dfc1, renc_w, BT_renc,
      ctx_w, att1_w, BT_ctxatt,
      d3w, CWT3, c2w, BtC2, c3w, BtC3, d1w, BD1, d2w, BD2, state, SBF, TOTb);

  // 2-6. fused parallel-path stages (enc || state || weight transposes)
  fuse_a<<<576, 256, 0, stream>>>(x, c1w, c1b, E1b, SBF, BT_renc, PB_renc);
  fuse_b<<<2176, 256, 0, stream>>>(PB_renc, renc_b, TOTb, E1b, BtC2, E2b,
                                   efc_w, BT_efc, dfc2_w, BT_dfc2);
  fuse_c<<<720, 256, 0, stream>>>(TOTb, BT_core, PB_core, E2b, c2b, BtC3, c3b, E3b);
  fuse_d<<<3072, 256, 0, stream>>>(PB_core, core_b, C1b, E3b, BT_efc, PB_efc);
  fuse_e<<<888, 256, 0, stream>>>(C1b, BT_ctxatt, PB_ctxatt, PB_efc, efc_b, TOTb+512);

  // 7. attention-weighted effect
  ctx_att_effect<<<384, 448, 0, stream>>>(PB_ctxatt, ctx_b, att1_b, att2_w, att2_b, TOTb);

  // 8-9. combine
  gemm_mfma<<<dim3(4,6,8), 256, 0, stream>>>(TOTb, BT_out, PB_out, 384, 250, 1024, 128);
  reduce_ns<<<384, 256, 0, stream>>>(PB_out, out_b, XRb, sout, 384, 250, 8);

  // 10-12. decoder FC
  gemm_mfma<<<dim3(8,6,4), 256, 0, stream>>>(XRb, BT_dfc1, PB_dfc1, 384, 512, 256, 64);
  reduce_ln<<<384, 256, 0, stream>>>(PB_dfc1, dfc1_b, G1b, 384, 512, 4, 512, 1, 1, -1);
  gemm_mfma<<<dim3(64,6,1), 256, 0, stream>>>(G1b, BT_dfc2, PB_dfc2, 384, 4096, 512, 512);

  // 13-14. fused dfc2-LN + decoder conv1+2, then conv3
  dec_ln_conv12<<<384, 256, 0, stream>>>(PB_dfc2, dfc2_b, BD1, d1b, BD2, d2b, D2b);
  dec_conv3_ig<<<768, 256, 0, stream>>>(D2b, CWT3, d3b, xout);

  (void)in_sizes; (void)n_in; (void)out_size; (void)ws_size;
}